// Round 8
// baseline (233.185 us; speedup 1.0000x reference)
//
#include <hip/hip_runtime.h>
#include <hip/hip_bf16.h>

#define N_IMG 2
#define HW 65536
#define PRE 1024
#define POST 256
#define NBIN 4096
#define SORTN 4096
#define PAIRCAP 131072
#define NMS_THR 0.7f
#define SCORE_T 0.1f
#define MIN_SZ 4.0f

// ---------- sortable key helpers ----------
__device__ __forceinline__ unsigned int fkey(float f) {
    unsigned int u = __float_as_uint(f);
    return u ^ ((u & 0x80000000u) ? 0xFFFFFFFFu : 0x80000000u);
}
__device__ __forceinline__ float unfkey(unsigned int k) {
    unsigned int u = (k & 0x80000000u) ? (k ^ 0x80000000u) : ~k;
    return __uint_as_float(u);
}
__device__ __forceinline__ unsigned long long readlane64(unsigned long long v, int l) {
    unsigned int lo = (unsigned int)__builtin_amdgcn_readlane((int)(unsigned int)v, l);
    unsigned int hi = (unsigned int)__builtin_amdgcn_readlane((int)(unsigned int)(v >> 32), l);
    return ((unsigned long long)hi << 32) | (unsigned long long)lo;
}

// ============================================================================
// K0: zero masks / hist / counters
// ============================================================================
__global__ void k_init(unsigned long long* masks, unsigned int* hist, unsigned int* cnts) {
    int t = blockIdx.x * blockDim.x + threadIdx.x;        // 160*256 = 40960
    if (t < N_IMG * PRE * 16) masks[t] = 0ULL;            // 32768 words
    if (t < N_IMG * NBIN) hist[t] = 0u;
    if (t < 8) cnts[t] = 0u;                              // [0..1]=cand cnt, [2]=pair cnt
}

// ============================================================================
// K1: 12-bit-prefix histogram, wide (64 blocks)
// ============================================================================
__global__ void k_hista(const float* __restrict__ obj, unsigned int* hist) {
    int t = blockIdx.x * blockDim.x + threadIdx.x;        // 16384 threads
    const float4* o4 = (const float4*)obj;                // 32768 float4 total
#pragma unroll
    for (int k = 0; k < 2; ++k) {
        int p = t + k * 16384;
        int img = p >> 14;                                // 16384 float4 per image
        float4 v = o4[p];
        atomicAdd(&hist[img * NBIN + (fkey(v.x) >> 20)], 1u);
        atomicAdd(&hist[img * NBIN + (fkey(v.y) >> 20)], 1u);
        atomicAdd(&hist[img * NBIN + (fkey(v.z) >> 20)], 1u);
        atomicAdd(&hist[img * NBIN + (fkey(v.w) >> 20)], 1u);
    }
}

// ============================================================================
// K2: find threshold bin (proven R0-R3 logic, global hist)
// ============================================================================
__global__ void k_findbin(const unsigned int* __restrict__ hist, unsigned int* selB) {
    __shared__ unsigned int lh[NBIN];
    __shared__ unsigned int chunk[256];
    int img = blockIdx.x;
    int t = threadIdx.x;
    unsigned int s = 0;
    for (int k = 0; k < 16; ++k) {
        unsigned int v = hist[img * NBIN + t * 16 + k];
        lh[t * 16 + k] = v;
        s += v;
    }
    chunk[t] = s;
    __syncthreads();
    if (t == 0) {
        unsigned int run = 0;
        int c;
        for (c = 255; c >= 0; --c) {
            if (run + chunk[c] >= PRE) break;
            run += chunk[c];
        }
        unsigned int B = 0;
        for (int b = c * 16 + 15; b >= c * 16; --b) {
            if (run + lh[b] >= PRE) { B = (unsigned int)b; break; }
            run += lh[b];
        }
        selB[img] = B;
    }
}

// ============================================================================
// K3: compact candidates to global cbuf, wide (64 blocks)
// ============================================================================
__global__ void k_compact(const float* __restrict__ obj, const unsigned int* __restrict__ selB,
                          unsigned int* cnts, unsigned long long* cbuf) {
    int t = blockIdx.x * blockDim.x + threadIdx.x;
    const float4* o4 = (const float4*)obj;
#pragma unroll
    for (int k = 0; k < 2; ++k) {
        int p = t + k * 16384;
        int img = p >> 14;
        unsigned int B = selB[img];
        float4 v = o4[p];
        float vs[4] = {v.x, v.y, v.z, v.w};
#pragma unroll
        for (int c = 0; c < 4; ++c) {
            unsigned int key = fkey(vs[c]);
            if ((key >> 20) >= B) {
                unsigned int i = (unsigned int)((p & 16383) * 4 + c);   // elem within image
                unsigned int pos = atomicAdd(&cnts[img], 1u);
                if (pos < SORTN)
                    cbuf[img * SORTN + pos] = ((unsigned long long)key << 32) |
                                              (unsigned long long)(0xFFFFFFFFu - i);
            }
        }
    }
}

// ============================================================================
// K4: counting-rank sort (order-independent -> deterministic), 32 blocks
// ============================================================================
__global__ __launch_bounds__(256) void k_rank(const unsigned int* __restrict__ cnts,
                                              const unsigned long long* __restrict__ cbuf,
                                              unsigned long long* sorted) {
    __shared__ unsigned long long keys[SORTN];            // 32 KB
    int img = blockIdx.x >> 4;                            // 16 slices per image
    int slice = blockIdx.x & 15;
    unsigned int M = cnts[img]; if (M > SORTN) M = SORTN;
    for (unsigned int i = threadIdx.x; i < M; i += 256) keys[i] = cbuf[img * SORTN + i];
    __syncthreads();
    unsigned int cid = (unsigned int)slice * 256 + threadIdx.x;
    if (cid < M) {
        unsigned long long c = keys[cid];
        unsigned int r = 0;
        for (unsigned int j = 0; j < M; ++j) r += (keys[j] > c) ? 1u : 0u;
        if (r < PRE) sorted[img * PRE + r] = c;           // keys unique -> ranks unique
    }
}

// ============================================================================
// K5: decode top-1024, wide (16 blocks x 128)
// ============================================================================
__global__ __launch_bounds__(128) void k_decode(const unsigned long long* __restrict__ sorted,
                                                const float* __restrict__ boxreg,
                                                float* boxes, float* corn, float4* circ,
                                                unsigned long long* vmask, float* tscr) {
    int g = blockIdx.x * 128 + threadIdx.x;               // 0..2047
    int img = g >> 10;
    int t = g & 1023;
    unsigned long long v = sorted[g];
    unsigned int key = (unsigned int)(v >> 32);
    unsigned int idx = (0xFFFFFFFFu - (unsigned int)(v & 0xFFFFFFFFULL)) & 0xFFFFu;
    float sc = unfkey(key);
    int h = (int)(idx >> 8);
    int w = (int)(idx & 255u);
    const float* rg = boxreg + (size_t)img * 5 * HW;
    float t_ = rg[0 * HW + idx] * 1024.0f;
    float rr = rg[1 * HW + idx] * 1024.0f;
    float bb = rg[2 * HW + idx] * 1024.0f;
    float ll = rg[3 * HW + idx] * 1024.0f;
    float ang = (rg[4 * HW + idx] - 0.5f) * 90.0f;
    float wd = ll + rr;
    float ht = t_ + bb;
    float xc = (float)w * 4.0f + 0.5f * (rr - ll);
    float yc = (float)h * 4.0f + 0.5f * (bb - t_);
    xc = fminf(fmaxf(xc, 0.0f), 1023.0f);
    yc = fminf(fmaxf(yc, 0.0f), 1023.0f);
    bool valid = (sc > SCORE_T) && (wd >= MIN_SZ) && (ht >= MIN_SZ);

    float* bx = boxes + (size_t)g * 5;
    bx[0] = xc; bx[1] = yc; bx[2] = wd; bx[3] = ht; bx[4] = ang;
    tscr[g] = sc;

    float th = ang * (float)(3.14159265358979323846 / 180.0);
    float c = cosf(th), s = sinf(th);
    const float dxs[4] = {-0.5f, 0.5f, 0.5f, -0.5f};
    const float dys[4] = {-0.5f, -0.5f, 0.5f, 0.5f};
    float* cr = corn + (size_t)g * 8;
#pragma unroll
    for (int k = 0; k < 4; ++k) {
        float dx = dxs[k] * wd, dy = dys[k] * ht;
        cr[2 * k]     = xc + dx * c - dy * s;
        cr[2 * k + 1] = yc + dx * s + dy * c;
    }
    circ[g] = make_float4(xc, yc, 0.5f * sqrtf(wd * wd + ht * ht) + 0.01f, wd * ht);

    unsigned long long bal = __ballot(valid ? 1 : 0);
    if ((t & 63) == 0) vmask[img * 16 + (t >> 6)] = bal;  // blocks don't straddle images
}

// ============================================================================
// K6: circle-prune pair enumeration with block-LDS compaction (512 blocks)
// ============================================================================
__global__ __launch_bounds__(256) void k_pairs(const float4* __restrict__ circ,
                                               unsigned int* cnts, unsigned int* pairs) {
    __shared__ unsigned int lbuf[1024];
    __shared__ unsigned int lcnt, lbase;
    if (threadIdx.x == 0) lcnt = 0;
    __syncthreads();
    int t0 = blockIdx.x * 256 + threadIdx.x;              // 131072 threads
#pragma unroll
    for (int k = 0; k < 16; ++k) {
        int p = t0 + k * 131072;                          // 2*1024*1024 pairs
        int img = p >> 20;
        int r = p & 1048575;
        int i = r >> 10, j = r & 1023;
        if (j > i) {
            float4 a = circ[img * PRE + i];
            float4 b = circ[img * PRE + j];
            float dx = b.x - a.x, dy = b.y - a.y, rr = a.z + b.z;
            if (dx * dx + dy * dy <= rr * rr) {
                unsigned int pr = ((unsigned int)img << 20) | ((unsigned int)i << 10) | (unsigned int)j;
                unsigned int pos = atomicAdd(&lcnt, 1u);
                if (pos < 1024) lbuf[pos] = pr;
                else {
                    unsigned int gp = atomicAdd(&cnts[2], 1u);
                    if (gp < PAIRCAP) pairs[gp] = pr;
                }
            }
        }
    }
    __syncthreads();
    unsigned int n = lcnt; if (n > 1024) n = 1024;
    if (threadIdx.x == 0) lbase = atomicAdd(&cnts[2], n);
    __syncthreads();
    unsigned int base = lbase;
    for (unsigned int q = threadIdx.x; q < n; q += 256) {
        unsigned int gp = base + q;
        if (gp < PAIRCAP) pairs[gp] = lbuf[q];
    }
}

// ============================================================================
// K7: dense Sutherland-Hodgman clip per surviving pair; LDS [slot][tid] scratch
// ============================================================================
__global__ __launch_bounds__(256) void k_clip(const unsigned int* __restrict__ cnts,
                                              const unsigned int* __restrict__ pairs,
                                              const float* __restrict__ corn,
                                              const float4* __restrict__ circ,
                                              unsigned long long* masks) {
    __shared__ float SPX[8][256], SPY[8][256], SQX[8][256], SQY[8][256];   // 32 KB
    int tid = threadIdx.x;
    unsigned int total = cnts[2]; if (total > PAIRCAP) total = PAIRCAP;
    for (unsigned int p = blockIdx.x * 256 + tid; p < total; p += 128 * 256) {
        unsigned int pr = pairs[p];
        int img = (int)(pr >> 20);
        int i = (int)((pr >> 10) & 1023);
        int j = (int)(pr & 1023);
        int ra = img * PRE + i, rb = img * PRE + j;
        const float4* ca = (const float4*)(corn + (size_t)ra * 8);
        float4 a0 = ca[0], a1 = ca[1];
        const float4* cb = (const float4*)(corn + (size_t)rb * 8);
        float4 b0 = cb[0], b1 = cb[1];
        float cbx[4] = {b0.x, b0.z, b1.x, b1.z};
        float cby[4] = {b0.y, b0.w, b1.y, b1.w};
        SPX[0][tid] = a0.x; SPY[0][tid] = a0.y;
        SPX[1][tid] = a0.z; SPY[1][tid] = a0.w;
        SPX[2][tid] = a1.x; SPY[2][tid] = a1.y;
        SPX[3][tid] = a1.z; SPY[3][tid] = a1.w;
        int n = 4;
#pragma unroll
        for (int e = 0; e < 4; ++e) {
            float (*PX)[256] = (e & 1) ? SQX : SPX;       // static after unroll
            float (*PY)[256] = (e & 1) ? SQY : SPY;
            float (*QX)[256] = (e & 1) ? SPX : SQX;
            float (*QY)[256] = (e & 1) ? SPY : SQY;
            float p1x = cbx[e], p1y = cby[e];
            int e2 = (e + 1) & 3;
            float ex = cbx[e2] - p1x, ey = cby[e2] - p1y;
            int m = 0;
            for (int k = 0; k < n; ++k) {
                int kn = (k + 1 < n) ? k + 1 : 0;
                float cx_ = PX[k][tid], cy_ = PY[k][tid];
                float nx_ = PX[kn][tid], ny_ = PY[kn][tid];
                float dc = ex * (cy_ - p1y) - ey * (cx_ - p1x);
                float dn = ex * (ny_ - p1y) - ey * (nx_ - p1x);
                bool ic = dc >= 0.0f;
                bool inx = dn >= 0.0f;
                if (ic && m < 8) { QX[m][tid] = cx_; QY[m][tid] = cy_; ++m; }
                if ((ic != inx) && m < 8) {
                    float den = dc - dn;
                    float safe = (fabsf(den) > 1e-9f) ? den : 1.0f;
                    float tt = dc / safe;
                    QX[m][tid] = cx_ + tt * (nx_ - cx_);
                    QY[m][tid] = cy_ + tt * (ny_ - cy_);
                    ++m;
                }
            }
            n = m;
        }
        // e=0:P->Q, e=1:Q->P, e=2:P->Q, e=3:Q->P  => final polygon in SPX/SPY
        float inter = 0.0f;
        if (n >= 3) {
            float s = 0.0f;
            for (int k = 0; k < n; ++k) {
                int kn = (k + 1 < n) ? k + 1 : 0;
                s += SPX[k][tid] * SPY[kn][tid] - SPX[kn][tid] * SPY[k][tid];
            }
            inter = 0.5f * fabsf(s);
        }
        float uni = circ[ra].w + circ[rb].w - inter;
        float iou = inter / fmaxf(uni, 1e-9f);
        if (iou > NMS_THR)
            atomicOr(&masks[(size_t)ra * 16 + (j >> 6)], 1ULL << (j & 63));
    }
}

// ============================================================================
// K8: greedy NMS (LDS-staged masks, early-stop, batch-4) + output  [R7, unchanged]
// ============================================================================
__global__ __launch_bounds__(1024) void k_nms_out(const unsigned long long* __restrict__ masks,
                                                  const unsigned long long* __restrict__ vmask,
                                                  const float* __restrict__ boxes,
                                                  const float* __restrict__ tscr,
                                                  float* __restrict__ out) {
    __shared__ unsigned long long lm[PRE * 16];   // 128 KB
    __shared__ unsigned short keptIdx[POST];
    __shared__ int sTotal;
    int img = blockIdx.x;
    int t = threadIdx.x;
    const unsigned long long* mbase = masks + (size_t)img * PRE * 16;
    {
        const ulonglong2* src = (const ulonglong2*)mbase;
        ulonglong2* dst = (ulonglong2*)lm;
#pragma unroll
        for (int k = 0; k < 8; ++k) dst[t + k * 1024] = src[t + k * 1024];
    }
    __syncthreads();

    if (t < 64) {
        int lane = t;
        int lw = lane & 15;
        unsigned long long vmw = vmask[img * 16 + lw];
        unsigned long long supw = 0ULL;
        int cnt = 0;
        for (int b = 0; b < 16 && cnt < POST; ++b) {
            unsigned long long avail = readlane64(vmw, b) & ~readlane64(supw, b);
            while (avail && cnt < POST) {
                unsigned long long a = avail;
                int d0 = __ffsll((long long)a) - 1; a &= a - 1;
                int d1 = a ? __ffsll((long long)a) - 1 : 64; a &= a - 1;
                int d2 = a ? __ffsll((long long)a) - 1 : 64; a &= a - 1;
                int d3 = a ? __ffsll((long long)a) - 1 : 64; a &= a - 1;
                int r0 = b * 64 + d0;
                int r1 = b * 64 + (d1 & 63);
                int r2 = b * 64 + (d2 & 63);
                int r3 = b * 64 + (d3 & 63);
                unsigned long long w0 = lm[r0 * 16 + lw];
                unsigned long long w1 = lm[r1 * 16 + lw];
                unsigned long long w2 = lm[r2 * 16 + lw];
                unsigned long long w3 = lm[r3 * 16 + lw];
                unsigned long long sb = readlane64(w0, b);
                supw |= w0;
                if (lane == 0) keptIdx[cnt] = (unsigned short)r0;
                ++cnt;
                if (d1 < 64 && cnt < POST && !((sb >> d1) & 1ULL)) {
                    sb |= readlane64(w1, b); supw |= w1;
                    if (lane == 0) keptIdx[cnt] = (unsigned short)r1;
                    ++cnt;
                }
                if (d2 < 64 && cnt < POST && !((sb >> d2) & 1ULL)) {
                    sb |= readlane64(w2, b); supw |= w2;
                    if (lane == 0) keptIdx[cnt] = (unsigned short)r2;
                    ++cnt;
                }
                if (d3 < 64 && cnt < POST && !((sb >> d3) & 1ULL)) {
                    sb |= readlane64(w3, b); supw |= w3;
                    if (lane == 0) keptIdx[cnt] = (unsigned short)r3;
                    ++cnt;
                }
                avail = a & ~sb;
            }
        }
        if (lane == 0) sTotal = cnt;
    }
    __syncthreads();

    int total = sTotal;
    if (t < POST) {
        float v0 = 0.f, v1 = 0.f, v2 = 0.f, v3 = 0.f, v4 = 0.f, v5 = 0.f;
        if (t < total) {
            int i = keptIdx[t];
            const float* b = boxes + (size_t)(img * PRE + i) * 5;
            v0 = b[0]; v1 = b[1]; v2 = b[2]; v3 = b[3]; v4 = b[4];
            v5 = tscr[img * PRE + i];
        }
        float* o2 = out + (size_t)(img * POST + t) * 6;
        o2[0] = v0; o2[1] = v1; o2[2] = v2; o2[3] = v3; o2[4] = v4; o2[5] = v5;
    }
}

// ---------- workspace layout (16-byte aligned where vector-cast) ----------
enum : size_t {
    OFF_BOX  = 0,          // 2*1024*5*4  = 40960
    OFF_CORN = 40960,      // 2*1024*8*4  = 65536  -> 106496   (16-aligned, float4 reads)
    OFF_CIRC = 106496,     // 2*1024*16   = 32768  -> 139264   (float4)
    OFF_VMSK = 139264,     // 256                  -> 139520
    OFF_TSCR = 139520,     // 8192                 -> 147712
    OFF_MASK = 147712,     // 2*1024*16*8 = 262144 -> 409856   (16-aligned, ulonglong2 reads)
    OFF_HIST = 409856,     // 2*4096*4    = 32768  -> 442624
    OFF_CNTS = 442624,     // 32                   -> 442656
    OFF_SELB = 442656,     // 16                   -> 442672
    OFF_CBUF = 442672,     // 2*4096*8    = 65536  -> 508208
    OFF_SORT = 508208,     // 2*1024*8    = 16384  -> 524592
    OFF_PAIR = 524592,     // 131072*4    = 524288 -> 1048880
};

extern "C" void kernel_launch(void* const* d_in, const int* in_sizes, int n_in,
                              void* d_out, int out_size, void* d_ws, size_t ws_size,
                              hipStream_t stream) {
    const float* obj = (const float*)d_in[0];       // (2,1,256,256) f32
    const float* boxreg = (const float*)d_in[1];    // (2,5,256,256) f32
    float* out = (float*)d_out;                     // (2,256,6) f32

    char* w = (char*)d_ws;
    float* boxes = (float*)(w + OFF_BOX);
    float* corn = (float*)(w + OFF_CORN);
    float4* circ = (float4*)(w + OFF_CIRC);
    unsigned long long* vmask = (unsigned long long*)(w + OFF_VMSK);
    float* tscr = (float*)(w + OFF_TSCR);
    unsigned long long* masks = (unsigned long long*)(w + OFF_MASK);
    unsigned int* hist = (unsigned int*)(w + OFF_HIST);
    unsigned int* cnts = (unsigned int*)(w + OFF_CNTS);
    unsigned int* selB = (unsigned int*)(w + OFF_SELB);
    unsigned long long* cbuf = (unsigned long long*)(w + OFF_CBUF);
    unsigned long long* sorted = (unsigned long long*)(w + OFF_SORT);
    unsigned int* pairs = (unsigned int*)(w + OFF_PAIR);

    k_init<<<160, 256, 0, stream>>>(masks, hist, cnts);
    k_hista<<<64, 256, 0, stream>>>(obj, hist);
    k_findbin<<<N_IMG, 256, 0, stream>>>(hist, selB);
    k_compact<<<64, 256, 0, stream>>>(obj, selB, cnts, cbuf);
    k_rank<<<32, 256, 0, stream>>>(cnts, cbuf, sorted);
    k_decode<<<16, 128, 0, stream>>>(sorted, boxreg, boxes, corn, circ, vmask, tscr);
    k_pairs<<<512, 256, 0, stream>>>(circ, cnts, pairs);
    k_clip<<<128, 256, 0, stream>>>(cnts, pairs, corn, circ, masks);
    k_nms_out<<<N_IMG, 1024, 0, stream>>>(masks, vmask, boxes, tscr, out);
}

// Round 9
// 168.266 us; speedup vs baseline: 1.3858x; 1.3858x over previous
//
#include <hip/hip_runtime.h>
#include <hip/hip_bf16.h>

#define N_IMG 2
#define HW 65536
#define PRE 1024
#define POST 256
#define NBIN 4096
#define SORTN 4096
#define PAIRCAP 131072
#define NMS_THR 0.7f
#define SCORE_T 0.1f
#define MIN_SZ 4.0f

// ---------- sortable key helpers ----------
__device__ __forceinline__ unsigned int fkey(float f) {
    unsigned int u = __float_as_uint(f);
    return u ^ ((u & 0x80000000u) ? 0xFFFFFFFFu : 0x80000000u);
}
__device__ __forceinline__ float unfkey(unsigned int k) {
    unsigned int u = (k & 0x80000000u) ? (k ^ 0x80000000u) : ~k;
    return __uint_as_float(u);
}
__device__ __forceinline__ unsigned long long readlane64(unsigned long long v, int l) {
    unsigned int lo = (unsigned int)__builtin_amdgcn_readlane((int)(unsigned int)v, l);
    unsigned int hi = (unsigned int)__builtin_amdgcn_readlane((int)(unsigned int)(v >> 32), l);
    return ((unsigned long long)hi << 32) | (unsigned long long)lo;
}

// ============================================================================
// K0: zero masks / hist / counters
// ============================================================================
__global__ void k_init(unsigned long long* masks, unsigned int* hist, unsigned int* cnts) {
    int t = blockIdx.x * blockDim.x + threadIdx.x;        // 160*256 = 40960
    if (t < N_IMG * PRE * 16) masks[t] = 0ULL;            // 32768 words
    if (t < N_IMG * NBIN) hist[t] = 0u;
    if (t < 8) cnts[t] = 0u;                              // [0..1]=cand cnt, [2]=pair cnt
}

// ============================================================================
// K1: 12-bit-prefix histogram — per-block LDS hist, sparse global merge.
// (R8 lesson: 131K global atomics on ~200 hot bins = 102us of cross-XCD RMW.)
// ============================================================================
__global__ __launch_bounds__(1024) void k_hista(const float* __restrict__ obj,
                                                unsigned int* hist) {
    __shared__ unsigned int lh[NBIN];
    int img = blockIdx.x >> 3;                            // 8 blocks per image
    int seg = blockIdx.x & 7;
    for (int i = threadIdx.x; i < NBIN; i += 1024) lh[i] = 0u;
    __syncthreads();
    const float4* o4 = (const float4*)(obj + (size_t)img * HW);
    int base = seg * 2048;                                // 2048 float4 per segment
#pragma unroll
    for (int k = 0; k < 2; ++k) {
        float4 v = o4[base + threadIdx.x + k * 1024];
        atomicAdd(&lh[fkey(v.x) >> 20], 1u);
        atomicAdd(&lh[fkey(v.y) >> 20], 1u);
        atomicAdd(&lh[fkey(v.z) >> 20], 1u);
        atomicAdd(&lh[fkey(v.w) >> 20], 1u);
    }
    __syncthreads();
    for (int i = threadIdx.x; i < NBIN; i += 1024) {
        unsigned int c = lh[i];
        if (c) atomicAdd(&hist[img * NBIN + i], c);       // ~200 nonzero bins/block
    }
}

// ============================================================================
// K2: find threshold bin (proven R0-R3 logic, global hist)
// ============================================================================
__global__ void k_findbin(const unsigned int* __restrict__ hist, unsigned int* selB) {
    __shared__ unsigned int lh[NBIN];
    __shared__ unsigned int chunk[256];
    int img = blockIdx.x;
    int t = threadIdx.x;
    unsigned int s = 0;
    for (int k = 0; k < 16; ++k) {
        unsigned int v = hist[img * NBIN + t * 16 + k];
        lh[t * 16 + k] = v;
        s += v;
    }
    chunk[t] = s;
    __syncthreads();
    if (t == 0) {
        unsigned int run = 0;
        int c;
        for (c = 255; c >= 0; --c) {
            if (run + chunk[c] >= PRE) break;
            run += chunk[c];
        }
        unsigned int B = 0;
        for (int b = c * 16 + 15; b >= c * 16; --b) {
            if (run + lh[b] >= PRE) { B = (unsigned int)b; break; }
            run += lh[b];
        }
        selB[img] = B;
    }
}

// ============================================================================
// K3: compact candidates to global cbuf, wide (64 blocks)
// ============================================================================
__global__ void k_compact(const float* __restrict__ obj, const unsigned int* __restrict__ selB,
                          unsigned int* cnts, unsigned long long* cbuf) {
    int t = blockIdx.x * blockDim.x + threadIdx.x;
    const float4* o4 = (const float4*)obj;
#pragma unroll
    for (int k = 0; k < 2; ++k) {
        int p = t + k * 16384;
        int img = p >> 14;
        unsigned int B = selB[img];
        float4 v = o4[p];
        float vs[4] = {v.x, v.y, v.z, v.w};
#pragma unroll
        for (int c = 0; c < 4; ++c) {
            unsigned int key = fkey(vs[c]);
            if ((key >> 20) >= B) {
                unsigned int i = (unsigned int)((p & 16383) * 4 + c);   // elem within image
                unsigned int pos = atomicAdd(&cnts[img], 1u);
                if (pos < SORTN)
                    cbuf[img * SORTN + pos] = ((unsigned long long)key << 32) |
                                              (unsigned long long)(0xFFFFFFFFu - i);
            }
        }
    }
}

// ============================================================================
// K4: counting-rank sort (order-independent -> deterministic), 32 blocks
// ============================================================================
__global__ __launch_bounds__(256) void k_rank(const unsigned int* __restrict__ cnts,
                                              const unsigned long long* __restrict__ cbuf,
                                              unsigned long long* sorted) {
    __shared__ unsigned long long keys[SORTN];            // 32 KB
    int img = blockIdx.x >> 4;                            // 16 slices per image
    int slice = blockIdx.x & 15;
    unsigned int M = cnts[img]; if (M > SORTN) M = SORTN;
    for (unsigned int i = threadIdx.x; i < M; i += 256) keys[i] = cbuf[img * SORTN + i];
    __syncthreads();
    unsigned int cid = (unsigned int)slice * 256 + threadIdx.x;
    if (cid < M) {
        unsigned long long c = keys[cid];
        unsigned int r = 0;
        for (unsigned int j = 0; j < M; ++j) r += (keys[j] > c) ? 1u : 0u;
        if (r < PRE) sorted[img * PRE + r] = c;           // keys unique -> ranks unique
    }
}

// ============================================================================
// K5: decode top-1024, wide (16 blocks x 128)
// ============================================================================
__global__ __launch_bounds__(128) void k_decode(const unsigned long long* __restrict__ sorted,
                                                const float* __restrict__ boxreg,
                                                float* boxes, float* corn, float4* circ,
                                                unsigned long long* vmask, float* tscr) {
    int g = blockIdx.x * 128 + threadIdx.x;               // 0..2047
    int img = g >> 10;
    int t = g & 1023;
    unsigned long long v = sorted[g];
    unsigned int key = (unsigned int)(v >> 32);
    unsigned int idx = (0xFFFFFFFFu - (unsigned int)(v & 0xFFFFFFFFULL)) & 0xFFFFu;
    float sc = unfkey(key);
    int h = (int)(idx >> 8);
    int w = (int)(idx & 255u);
    const float* rg = boxreg + (size_t)img * 5 * HW;
    float t_ = rg[0 * HW + idx] * 1024.0f;
    float rr = rg[1 * HW + idx] * 1024.0f;
    float bb = rg[2 * HW + idx] * 1024.0f;
    float ll = rg[3 * HW + idx] * 1024.0f;
    float ang = (rg[4 * HW + idx] - 0.5f) * 90.0f;
    float wd = ll + rr;
    float ht = t_ + bb;
    float xc = (float)w * 4.0f + 0.5f * (rr - ll);
    float yc = (float)h * 4.0f + 0.5f * (bb - t_);
    xc = fminf(fmaxf(xc, 0.0f), 1023.0f);
    yc = fminf(fmaxf(yc, 0.0f), 1023.0f);
    bool valid = (sc > SCORE_T) && (wd >= MIN_SZ) && (ht >= MIN_SZ);

    float* bx = boxes + (size_t)g * 5;
    bx[0] = xc; bx[1] = yc; bx[2] = wd; bx[3] = ht; bx[4] = ang;
    tscr[g] = sc;

    float th = ang * (float)(3.14159265358979323846 / 180.0);
    float c = cosf(th), s = sinf(th);
    const float dxs[4] = {-0.5f, 0.5f, 0.5f, -0.5f};
    const float dys[4] = {-0.5f, -0.5f, 0.5f, 0.5f};
    float* cr = corn + (size_t)g * 8;
#pragma unroll
    for (int k = 0; k < 4; ++k) {
        float dx = dxs[k] * wd, dy = dys[k] * ht;
        cr[2 * k]     = xc + dx * c - dy * s;
        cr[2 * k + 1] = yc + dx * s + dy * c;
    }
    circ[g] = make_float4(xc, yc, 0.5f * sqrtf(wd * wd + ht * ht) + 0.01f, wd * ht);

    unsigned long long bal = __ballot(valid ? 1 : 0);
    if ((t & 63) == 0) vmask[img * 16 + (t >> 6)] = bal;  // blocks don't straddle images
}

// ============================================================================
// K6: circle-prune pair enumeration, tiled: thread owns row i, sweeps a
// 256-wide j-chunk staged in LDS. Block-LDS compaction -> one global bump.
// ============================================================================
__global__ __launch_bounds__(256) void k_pairs(const float4* __restrict__ circ,
                                               unsigned int* cnts, unsigned int* pairs) {
    __shared__ float4 cj[256];                            // j-chunk circles (4 KB)
    __shared__ unsigned int lbuf[4096];                   // 16 KB
    __shared__ unsigned int lcnt, lbase;
    int blk = blockIdx.x;                                 // 32 blocks: img(2) x it(4) x jc(4)
    int img = blk >> 4;
    int it = (blk >> 2) & 3;
    int jc = blk & 3;
    int tid = threadIdx.x;
    if (tid == 0) lcnt = 0;
    int i = it * 256 + tid;                               // this thread's row
    float4 a = circ[img * PRE + i];
    cj[tid] = circ[img * PRE + jc * 256 + tid];
    __syncthreads();
#pragma unroll 4
    for (int q = 0; q < 256; ++q) {
        int j = jc * 256 + q;
        if (j > i) {
            float4 b = cj[q];
            float dx = b.x - a.x, dy = b.y - a.y, rr = a.z + b.z;
            if (dx * dx + dy * dy <= rr * rr) {
                unsigned int pr = ((unsigned int)img << 20) | ((unsigned int)i << 10) | (unsigned int)j;
                unsigned int pos = atomicAdd(&lcnt, 1u);
                if (pos < 4096) lbuf[pos] = pr;
                else {
                    unsigned int gp = atomicAdd(&cnts[2], 1u);
                    if (gp < PAIRCAP) pairs[gp] = pr;
                }
            }
        }
    }
    __syncthreads();
    unsigned int n = lcnt; if (n > 4096) n = 4096;
    if (tid == 0) lbase = atomicAdd(&cnts[2], n);
    __syncthreads();
    unsigned int base = lbase;
    for (unsigned int q = tid; q < n; q += 256) {
        unsigned int gp = base + q;
        if (gp < PAIRCAP) pairs[gp] = lbuf[q];
    }
}

// ============================================================================
// K7: dense Sutherland-Hodgman clip per surviving pair; LDS [slot][tid] scratch
// ============================================================================
__global__ __launch_bounds__(256) void k_clip(const unsigned int* __restrict__ cnts,
                                              const unsigned int* __restrict__ pairs,
                                              const float* __restrict__ corn,
                                              const float4* __restrict__ circ,
                                              unsigned long long* masks) {
    __shared__ float SPX[8][256], SPY[8][256], SQX[8][256], SQY[8][256];   // 32 KB
    int tid = threadIdx.x;
    unsigned int total = cnts[2]; if (total > PAIRCAP) total = PAIRCAP;
    for (unsigned int p = blockIdx.x * 256 + tid; p < total; p += 128 * 256) {
        unsigned int pr = pairs[p];
        int img = (int)(pr >> 20);
        int i = (int)((pr >> 10) & 1023);
        int j = (int)(pr & 1023);
        int ra = img * PRE + i, rb = img * PRE + j;
        const float4* ca = (const float4*)(corn + (size_t)ra * 8);
        float4 a0 = ca[0], a1 = ca[1];
        const float4* cb = (const float4*)(corn + (size_t)rb * 8);
        float4 b0 = cb[0], b1 = cb[1];
        float cbx[4] = {b0.x, b0.z, b1.x, b1.z};
        float cby[4] = {b0.y, b0.w, b1.y, b1.w};
        SPX[0][tid] = a0.x; SPY[0][tid] = a0.y;
        SPX[1][tid] = a0.z; SPY[1][tid] = a0.w;
        SPX[2][tid] = a1.x; SPY[2][tid] = a1.y;
        SPX[3][tid] = a1.z; SPY[3][tid] = a1.w;
        int n = 4;
#pragma unroll
        for (int e = 0; e < 4; ++e) {
            float (*PX)[256] = (e & 1) ? SQX : SPX;       // static after unroll
            float (*PY)[256] = (e & 1) ? SQY : SPY;
            float (*QX)[256] = (e & 1) ? SPX : SQX;
            float (*QY)[256] = (e & 1) ? SPY : SQY;
            float p1x = cbx[e], p1y = cby[e];
            int e2 = (e + 1) & 3;
            float ex = cbx[e2] - p1x, ey = cby[e2] - p1y;
            int m = 0;
            for (int k = 0; k < n; ++k) {
                int kn = (k + 1 < n) ? k + 1 : 0;
                float cx_ = PX[k][tid], cy_ = PY[k][tid];
                float nx_ = PX[kn][tid], ny_ = PY[kn][tid];
                float dc = ex * (cy_ - p1y) - ey * (cx_ - p1x);
                float dn = ex * (ny_ - p1y) - ey * (nx_ - p1x);
                bool ic = dc >= 0.0f;
                bool inx = dn >= 0.0f;
                if (ic && m < 8) { QX[m][tid] = cx_; QY[m][tid] = cy_; ++m; }
                if ((ic != inx) && m < 8) {
                    float den = dc - dn;
                    float safe = (fabsf(den) > 1e-9f) ? den : 1.0f;
                    float tt = dc / safe;
                    QX[m][tid] = cx_ + tt * (nx_ - cx_);
                    QY[m][tid] = cy_ + tt * (ny_ - cy_);
                    ++m;
                }
            }
            n = m;
        }
        // e=0:P->Q, e=1:Q->P, e=2:P->Q, e=3:Q->P  => final polygon in SPX/SPY
        float inter = 0.0f;
        if (n >= 3) {
            float s = 0.0f;
            for (int k = 0; k < n; ++k) {
                int kn = (k + 1 < n) ? k + 1 : 0;
                s += SPX[k][tid] * SPY[kn][tid] - SPX[kn][tid] * SPY[k][tid];
            }
            inter = 0.5f * fabsf(s);
        }
        float uni = circ[ra].w + circ[rb].w - inter;
        float iou = inter / fmaxf(uni, 1e-9f);
        if (iou > NMS_THR)
            atomicOr(&masks[(size_t)ra * 16 + (j >> 6)], 1ULL << (j & 63));
    }
}

// ============================================================================
// K8: greedy NMS (LDS-staged masks, early-stop, batch-4) + output  [R7, unchanged]
// ============================================================================
__global__ __launch_bounds__(1024) void k_nms_out(const unsigned long long* __restrict__ masks,
                                                  const unsigned long long* __restrict__ vmask,
                                                  const float* __restrict__ boxes,
                                                  const float* __restrict__ tscr,
                                                  float* __restrict__ out) {
    __shared__ unsigned long long lm[PRE * 16];   // 128 KB
    __shared__ unsigned short keptIdx[POST];
    __shared__ int sTotal;
    int img = blockIdx.x;
    int t = threadIdx.x;
    const unsigned long long* mbase = masks + (size_t)img * PRE * 16;
    {
        const ulonglong2* src = (const ulonglong2*)mbase;
        ulonglong2* dst = (ulonglong2*)lm;
#pragma unroll
        for (int k = 0; k < 8; ++k) dst[t + k * 1024] = src[t + k * 1024];
    }
    __syncthreads();

    if (t < 64) {
        int lane = t;
        int lw = lane & 15;
        unsigned long long vmw = vmask[img * 16 + lw];
        unsigned long long supw = 0ULL;
        int cnt = 0;
        for (int b = 0; b < 16 && cnt < POST; ++b) {
            unsigned long long avail = readlane64(vmw, b) & ~readlane64(supw, b);
            while (avail && cnt < POST) {
                unsigned long long a = avail;
                int d0 = __ffsll((long long)a) - 1; a &= a - 1;
                int d1 = a ? __ffsll((long long)a) - 1 : 64; a &= a - 1;
                int d2 = a ? __ffsll((long long)a) - 1 : 64; a &= a - 1;
                int d3 = a ? __ffsll((long long)a) - 1 : 64; a &= a - 1;
                int r0 = b * 64 + d0;
                int r1 = b * 64 + (d1 & 63);
                int r2 = b * 64 + (d2 & 63);
                int r3 = b * 64 + (d3 & 63);
                unsigned long long w0 = lm[r0 * 16 + lw];
                unsigned long long w1 = lm[r1 * 16 + lw];
                unsigned long long w2 = lm[r2 * 16 + lw];
                unsigned long long w3 = lm[r3 * 16 + lw];
                unsigned long long sb = readlane64(w0, b);
                supw |= w0;
                if (lane == 0) keptIdx[cnt] = (unsigned short)r0;
                ++cnt;
                if (d1 < 64 && cnt < POST && !((sb >> d1) & 1ULL)) {
                    sb |= readlane64(w1, b); supw |= w1;
                    if (lane == 0) keptIdx[cnt] = (unsigned short)r1;
                    ++cnt;
                }
                if (d2 < 64 && cnt < POST && !((sb >> d2) & 1ULL)) {
                    sb |= readlane64(w2, b); supw |= w2;
                    if (lane == 0) keptIdx[cnt] = (unsigned short)r2;
                    ++cnt;
                }
                if (d3 < 64 && cnt < POST && !((sb >> d3) & 1ULL)) {
                    sb |= readlane64(w3, b); supw |= w3;
                    if (lane == 0) keptIdx[cnt] = (unsigned short)r3;
                    ++cnt;
                }
                avail = a & ~sb;
            }
        }
        if (lane == 0) sTotal = cnt;
    }
    __syncthreads();

    int total = sTotal;
    if (t < POST) {
        float v0 = 0.f, v1 = 0.f, v2 = 0.f, v3 = 0.f, v4 = 0.f, v5 = 0.f;
        if (t < total) {
            int i = keptIdx[t];
            const float* b = boxes + (size_t)(img * PRE + i) * 5;
            v0 = b[0]; v1 = b[1]; v2 = b[2]; v3 = b[3]; v4 = b[4];
            v5 = tscr[img * PRE + i];
        }
        float* o2 = out + (size_t)(img * POST + t) * 6;
        o2[0] = v0; o2[1] = v1; o2[2] = v2; o2[3] = v3; o2[4] = v4; o2[5] = v5;
    }
}

// ---------- workspace layout (16-byte aligned where vector-cast) ----------
enum : size_t {
    OFF_BOX  = 0,          // 2*1024*5*4  = 40960
    OFF_CORN = 40960,      // 2*1024*8*4  = 65536  -> 106496   (16-aligned, float4 reads)
    OFF_CIRC = 106496,     // 2*1024*16   = 32768  -> 139264   (float4)
    OFF_VMSK = 139264,     // 256                  -> 139520
    OFF_TSCR = 139520,     // 8192                 -> 147712
    OFF_MASK = 147712,     // 2*1024*16*8 = 262144 -> 409856   (16-aligned, ulonglong2 reads)
    OFF_HIST = 409856,     // 2*4096*4    = 32768  -> 442624
    OFF_CNTS = 442624,     // 32                   -> 442656
    OFF_SELB = 442656,     // 16                   -> 442672
    OFF_CBUF = 442672,     // 2*4096*8    = 65536  -> 508208
    OFF_SORT = 508208,     // 2*1024*8    = 16384  -> 524592
    OFF_PAIR = 524592,     // 131072*4    = 524288 -> 1048880
};

extern "C" void kernel_launch(void* const* d_in, const int* in_sizes, int n_in,
                              void* d_out, int out_size, void* d_ws, size_t ws_size,
                              hipStream_t stream) {
    const float* obj = (const float*)d_in[0];       // (2,1,256,256) f32
    const float* boxreg = (const float*)d_in[1];    // (2,5,256,256) f32
    float* out = (float*)d_out;                     // (2,256,6) f32

    char* w = (char*)d_ws;
    float* boxes = (float*)(w + OFF_BOX);
    float* corn = (float*)(w + OFF_CORN);
    float4* circ = (float4*)(w + OFF_CIRC);
    unsigned long long* vmask = (unsigned long long*)(w + OFF_VMSK);
    float* tscr = (float*)(w + OFF_TSCR);
    unsigned long long* masks = (unsigned long long*)(w + OFF_MASK);
    unsigned int* hist = (unsigned int*)(w + OFF_HIST);
    unsigned int* cnts = (unsigned int*)(w + OFF_CNTS);
    unsigned int* selB = (unsigned int*)(w + OFF_SELB);
    unsigned long long* cbuf = (unsigned long long*)(w + OFF_CBUF);
    unsigned long long* sorted = (unsigned long long*)(w + OFF_SORT);
    unsigned int* pairs = (unsigned int*)(w + OFF_PAIR);

    k_init<<<160, 256, 0, stream>>>(masks, hist, cnts);
    k_hista<<<16, 1024, 0, stream>>>(obj, hist);
    k_findbin<<<N_IMG, 256, 0, stream>>>(hist, selB);
    k_compact<<<64, 256, 0, stream>>>(obj, selB, cnts, cbuf);
    k_rank<<<32, 256, 0, stream>>>(cnts, cbuf, sorted);
    k_decode<<<16, 128, 0, stream>>>(sorted, boxreg, boxes, corn, circ, vmask, tscr);
    k_pairs<<<32, 256, 0, stream>>>(circ, cnts, pairs);
    k_clip<<<128, 256, 0, stream>>>(cnts, pairs, corn, circ, masks);
    k_nms_out<<<N_IMG, 1024, 0, stream>>>(masks, vmask, boxes, tscr, out);
}

// Round 10
// 122.889 us; speedup vs baseline: 1.8975x; 1.3692x over previous
//
#include <hip/hip_runtime.h>
#include <hip/hip_bf16.h>

#define N_IMG 2
#define HW 65536
#define PRE 1024
#define POST 256
#define NBIN 4096
#define SORTN 4096
#define PAIRCAP 131072
#define NMS_THR 0.7f
#define SCORE_T 0.1f
#define MIN_SZ 4.0f

// ---------- sortable key helpers ----------
__device__ __forceinline__ unsigned int fkey(float f) {
    unsigned int u = __float_as_uint(f);
    return u ^ ((u & 0x80000000u) ? 0xFFFFFFFFu : 0x80000000u);
}
__device__ __forceinline__ float unfkey(unsigned int k) {
    unsigned int u = (k & 0x80000000u) ? (k ^ 0x80000000u) : ~k;
    return __uint_as_float(u);
}
__device__ __forceinline__ unsigned long long readlane64(unsigned long long v, int l) {
    unsigned int lo = (unsigned int)__builtin_amdgcn_readlane((int)(unsigned int)v, l);
    unsigned int hi = (unsigned int)__builtin_amdgcn_readlane((int)(unsigned int)(v >> 32), l);
    return ((unsigned long long)hi << 32) | (unsigned long long)lo;
}

// ============================================================================
// K0: zero masks / hist / counters
// ============================================================================
__global__ void k_init(unsigned long long* masks, unsigned int* hist, unsigned int* cnts) {
    int t = blockIdx.x * blockDim.x + threadIdx.x;        // 160*256 = 40960
    if (t < N_IMG * PRE * 16) masks[t] = 0ULL;            // 32768 words
    if (t < N_IMG * NBIN) hist[t] = 0u;
    if (t < 8) cnts[t] = 0u;                              // [0..1]=cand cnt, [2]=pair cnt
}

// ============================================================================
// K1: 12-bit-prefix histogram — per-block LDS hist, sparse global merge.
// ============================================================================
__global__ __launch_bounds__(1024) void k_hista(const float* __restrict__ obj,
                                                unsigned int* hist) {
    __shared__ unsigned int lh[NBIN];
    int img = blockIdx.x >> 3;                            // 8 blocks per image
    int seg = blockIdx.x & 7;
    for (int i = threadIdx.x; i < NBIN; i += 1024) lh[i] = 0u;
    __syncthreads();
    const float4* o4 = (const float4*)(obj + (size_t)img * HW);
    int base = seg * 2048;                                // 2048 float4 per segment
#pragma unroll
    for (int k = 0; k < 2; ++k) {
        float4 v = o4[base + threadIdx.x + k * 1024];
        atomicAdd(&lh[fkey(v.x) >> 20], 1u);
        atomicAdd(&lh[fkey(v.y) >> 20], 1u);
        atomicAdd(&lh[fkey(v.z) >> 20], 1u);
        atomicAdd(&lh[fkey(v.w) >> 20], 1u);
    }
    __syncthreads();
    for (int i = threadIdx.x; i < NBIN; i += 1024) {
        unsigned int c = lh[i];
        if (c) atomicAdd(&hist[img * NBIN + i], c);       // ~200 nonzero bins/block
    }
}

// ============================================================================
// K2: find threshold bin (proven R0-R3 logic, global hist)
// ============================================================================
__global__ void k_findbin(const unsigned int* __restrict__ hist, unsigned int* selB) {
    __shared__ unsigned int lh[NBIN];
    __shared__ unsigned int chunk[256];
    int img = blockIdx.x;
    int t = threadIdx.x;
    unsigned int s = 0;
    for (int k = 0; k < 16; ++k) {
        unsigned int v = hist[img * NBIN + t * 16 + k];
        lh[t * 16 + k] = v;
        s += v;
    }
    chunk[t] = s;
    __syncthreads();
    if (t == 0) {
        unsigned int run = 0;
        int c;
        for (c = 255; c >= 0; --c) {
            if (run + chunk[c] >= PRE) break;
            run += chunk[c];
        }
        unsigned int B = 0;
        for (int b = c * 16 + 15; b >= c * 16; --b) {
            if (run + lh[b] >= PRE) { B = (unsigned int)b; break; }
            run += lh[b];
        }
        selB[img] = B;
    }
}

// ============================================================================
// K3: compact candidates — block-LDS aggregation, ONE global atomic per
// block per image. (R9 lesson: 3.4K device atomics on 2 hot counters = 50us.)
// Per k-iteration the image is uniform (k=0 -> img0, k=1 -> img1).
// ============================================================================
__global__ __launch_bounds__(256) void k_compact(const float* __restrict__ obj,
                                                 const unsigned int* __restrict__ selB,
                                                 unsigned int* cnts, unsigned long long* cbuf) {
    __shared__ unsigned long long lbuf[1024];             // max 256 thr x 4 elems
    __shared__ unsigned int lcnt, lbase;
    int t = blockIdx.x * 256 + threadIdx.x;               // 0..16383
    const float4* o4 = (const float4*)obj;
#pragma unroll
    for (int k = 0; k < 2; ++k) {
        if (threadIdx.x == 0) lcnt = 0;
        __syncthreads();
        int p = t + k * 16384;                            // img = k (uniform)
        int img = p >> 14;
        unsigned int B = selB[img];
        float4 v = o4[p];
        float vs[4] = {v.x, v.y, v.z, v.w};
#pragma unroll
        for (int c = 0; c < 4; ++c) {
            unsigned int key = fkey(vs[c]);
            if ((key >> 20) >= B) {
                unsigned int i = (unsigned int)((p & 16383) * 4 + c);   // elem within image
                unsigned int pos = atomicAdd(&lcnt, 1u);                // LDS atomic
                lbuf[pos] = ((unsigned long long)key << 32) |
                            (unsigned long long)(0xFFFFFFFFu - i);
            }
        }
        __syncthreads();
        if (threadIdx.x == 0) lbase = atomicAdd(&cnts[img], lcnt);      // 1 global atomic
        __syncthreads();
        unsigned int n = lcnt, base = lbase;
        for (unsigned int q = threadIdx.x; q < n; q += 256) {
            unsigned int gp = base + q;
            if (gp < SORTN) cbuf[img * SORTN + gp] = lbuf[q];
        }
        __syncthreads();                                  // protect lcnt reuse
    }
}

// ============================================================================
// K4: counting-rank sort (order-independent -> deterministic), 32 blocks
// ============================================================================
__global__ __launch_bounds__(256) void k_rank(const unsigned int* __restrict__ cnts,
                                              const unsigned long long* __restrict__ cbuf,
                                              unsigned long long* sorted) {
    __shared__ unsigned long long keys[SORTN];            // 32 KB
    int img = blockIdx.x >> 4;                            // 16 slices per image
    int slice = blockIdx.x & 15;
    unsigned int M = cnts[img]; if (M > SORTN) M = SORTN;
    for (unsigned int i = threadIdx.x; i < M; i += 256) keys[i] = cbuf[img * SORTN + i];
    __syncthreads();
    unsigned int cid = (unsigned int)slice * 256 + threadIdx.x;
    if (cid < M) {
        unsigned long long c = keys[cid];
        unsigned int r = 0;
        for (unsigned int j = 0; j < M; ++j) r += (keys[j] > c) ? 1u : 0u;
        if (r < PRE) sorted[img * PRE + r] = c;           // keys unique -> ranks unique
    }
}

// ============================================================================
// K5: decode top-1024, wide (16 blocks x 128)
// ============================================================================
__global__ __launch_bounds__(128) void k_decode(const unsigned long long* __restrict__ sorted,
                                                const float* __restrict__ boxreg,
                                                float* boxes, float* corn, float4* circ,
                                                unsigned long long* vmask, float* tscr) {
    int g = blockIdx.x * 128 + threadIdx.x;               // 0..2047
    int img = g >> 10;
    int t = g & 1023;
    unsigned long long v = sorted[g];
    unsigned int key = (unsigned int)(v >> 32);
    unsigned int idx = (0xFFFFFFFFu - (unsigned int)(v & 0xFFFFFFFFULL)) & 0xFFFFu;
    float sc = unfkey(key);
    int h = (int)(idx >> 8);
    int w = (int)(idx & 255u);
    const float* rg = boxreg + (size_t)img * 5 * HW;
    float t_ = rg[0 * HW + idx] * 1024.0f;
    float rr = rg[1 * HW + idx] * 1024.0f;
    float bb = rg[2 * HW + idx] * 1024.0f;
    float ll = rg[3 * HW + idx] * 1024.0f;
    float ang = (rg[4 * HW + idx] - 0.5f) * 90.0f;
    float wd = ll + rr;
    float ht = t_ + bb;
    float xc = (float)w * 4.0f + 0.5f * (rr - ll);
    float yc = (float)h * 4.0f + 0.5f * (bb - t_);
    xc = fminf(fmaxf(xc, 0.0f), 1023.0f);
    yc = fminf(fmaxf(yc, 0.0f), 1023.0f);
    bool valid = (sc > SCORE_T) && (wd >= MIN_SZ) && (ht >= MIN_SZ);

    float* bx = boxes + (size_t)g * 5;
    bx[0] = xc; bx[1] = yc; bx[2] = wd; bx[3] = ht; bx[4] = ang;
    tscr[g] = sc;

    float th = ang * (float)(3.14159265358979323846 / 180.0);
    float c = cosf(th), s = sinf(th);
    const float dxs[4] = {-0.5f, 0.5f, 0.5f, -0.5f};
    const float dys[4] = {-0.5f, -0.5f, 0.5f, 0.5f};
    float* cr = corn + (size_t)g * 8;
#pragma unroll
    for (int k = 0; k < 4; ++k) {
        float dx = dxs[k] * wd, dy = dys[k] * ht;
        cr[2 * k]     = xc + dx * c - dy * s;
        cr[2 * k + 1] = yc + dx * s + dy * c;
    }
    circ[g] = make_float4(xc, yc, 0.5f * sqrtf(wd * wd + ht * ht) + 0.01f, wd * ht);

    unsigned long long bal = __ballot(valid ? 1 : 0);
    if ((t & 63) == 0) vmask[img * 16 + (t >> 6)] = bal;  // blocks don't straddle images
}

// ============================================================================
// K6: circle-prune pair enumeration, tiled: thread owns row i, sweeps a
// 256-wide j-chunk staged in LDS. Block-LDS compaction -> one global bump.
// ============================================================================
__global__ __launch_bounds__(256) void k_pairs(const float4* __restrict__ circ,
                                               unsigned int* cnts, unsigned int* pairs) {
    __shared__ float4 cj[256];                            // j-chunk circles (4 KB)
    __shared__ unsigned int lbuf[4096];                   // 16 KB
    __shared__ unsigned int lcnt, lbase;
    int blk = blockIdx.x;                                 // 32 blocks: img(2) x it(4) x jc(4)
    int img = blk >> 4;
    int it = (blk >> 2) & 3;
    int jc = blk & 3;
    int tid = threadIdx.x;
    if (tid == 0) lcnt = 0;
    int i = it * 256 + tid;                               // this thread's row
    float4 a = circ[img * PRE + i];
    cj[tid] = circ[img * PRE + jc * 256 + tid];
    __syncthreads();
#pragma unroll 4
    for (int q = 0; q < 256; ++q) {
        int j = jc * 256 + q;
        if (j > i) {
            float4 b = cj[q];
            float dx = b.x - a.x, dy = b.y - a.y, rr = a.z + b.z;
            if (dx * dx + dy * dy <= rr * rr) {
                unsigned int pr = ((unsigned int)img << 20) | ((unsigned int)i << 10) | (unsigned int)j;
                unsigned int pos = atomicAdd(&lcnt, 1u);
                if (pos < 4096) lbuf[pos] = pr;
                else {
                    unsigned int gp = atomicAdd(&cnts[2], 1u);
                    if (gp < PAIRCAP) pairs[gp] = pr;
                }
            }
        }
    }
    __syncthreads();
    unsigned int n = lcnt; if (n > 4096) n = 4096;
    if (tid == 0) lbase = atomicAdd(&cnts[2], n);
    __syncthreads();
    unsigned int base = lbase;
    for (unsigned int q = tid; q < n; q += 256) {
        unsigned int gp = base + q;
        if (gp < PAIRCAP) pairs[gp] = lbuf[q];
    }
}

// ============================================================================
// K7: dense Sutherland-Hodgman clip per surviving pair; LDS [slot][tid] scratch
// ============================================================================
__global__ __launch_bounds__(256) void k_clip(const unsigned int* __restrict__ cnts,
                                              const unsigned int* __restrict__ pairs,
                                              const float* __restrict__ corn,
                                              const float4* __restrict__ circ,
                                              unsigned long long* masks) {
    __shared__ float SPX[8][256], SPY[8][256], SQX[8][256], SQY[8][256];   // 32 KB
    int tid = threadIdx.x;
    unsigned int total = cnts[2]; if (total > PAIRCAP) total = PAIRCAP;
    for (unsigned int p = blockIdx.x * 256 + tid; p < total; p += 128 * 256) {
        unsigned int pr = pairs[p];
        int img = (int)(pr >> 20);
        int i = (int)((pr >> 10) & 1023);
        int j = (int)(pr & 1023);
        int ra = img * PRE + i, rb = img * PRE + j;
        const float4* ca = (const float4*)(corn + (size_t)ra * 8);
        float4 a0 = ca[0], a1 = ca[1];
        const float4* cb = (const float4*)(corn + (size_t)rb * 8);
        float4 b0 = cb[0], b1 = cb[1];
        float cbx[4] = {b0.x, b0.z, b1.x, b1.z};
        float cby[4] = {b0.y, b0.w, b1.y, b1.w};
        SPX[0][tid] = a0.x; SPY[0][tid] = a0.y;
        SPX[1][tid] = a0.z; SPY[1][tid] = a0.w;
        SPX[2][tid] = a1.x; SPY[2][tid] = a1.y;
        SPX[3][tid] = a1.z; SPY[3][tid] = a1.w;
        int n = 4;
#pragma unroll
        for (int e = 0; e < 4; ++e) {
            float (*PX)[256] = (e & 1) ? SQX : SPX;       // static after unroll
            float (*PY)[256] = (e & 1) ? SQY : SPY;
            float (*QX)[256] = (e & 1) ? SPX : SQX;
            float (*QY)[256] = (e & 1) ? SPY : SQY;
            float p1x = cbx[e], p1y = cby[e];
            int e2 = (e + 1) & 3;
            float ex = cbx[e2] - p1x, ey = cby[e2] - p1y;
            int m = 0;
            for (int k = 0; k < n; ++k) {
                int kn = (k + 1 < n) ? k + 1 : 0;
                float cx_ = PX[k][tid], cy_ = PY[k][tid];
                float nx_ = PX[kn][tid], ny_ = PY[kn][tid];
                float dc = ex * (cy_ - p1y) - ey * (cx_ - p1x);
                float dn = ex * (ny_ - p1y) - ey * (nx_ - p1x);
                bool ic = dc >= 0.0f;
                bool inx = dn >= 0.0f;
                if (ic && m < 8) { QX[m][tid] = cx_; QY[m][tid] = cy_; ++m; }
                if ((ic != inx) && m < 8) {
                    float den = dc - dn;
                    float safe = (fabsf(den) > 1e-9f) ? den : 1.0f;
                    float tt = dc / safe;
                    QX[m][tid] = cx_ + tt * (nx_ - cx_);
                    QY[m][tid] = cy_ + tt * (ny_ - cy_);
                    ++m;
                }
            }
            n = m;
        }
        // e=0:P->Q, e=1:Q->P, e=2:P->Q, e=3:Q->P  => final polygon in SPX/SPY
        float inter = 0.0f;
        if (n >= 3) {
            float s = 0.0f;
            for (int k = 0; k < n; ++k) {
                int kn = (k + 1 < n) ? k + 1 : 0;
                s += SPX[k][tid] * SPY[kn][tid] - SPX[kn][tid] * SPY[k][tid];
            }
            inter = 0.5f * fabsf(s);
        }
        float uni = circ[ra].w + circ[rb].w - inter;
        float iou = inter / fmaxf(uni, 1e-9f);
        if (iou > NMS_THR)
            atomicOr(&masks[(size_t)ra * 16 + (j >> 6)], 1ULL << (j & 63));
    }
}

// ============================================================================
// K8: greedy NMS (LDS-staged masks, early-stop, batch-4) + output
// ============================================================================
__global__ __launch_bounds__(1024) void k_nms_out(const unsigned long long* __restrict__ masks,
                                                  const unsigned long long* __restrict__ vmask,
                                                  const float* __restrict__ boxes,
                                                  const float* __restrict__ tscr,
                                                  float* __restrict__ out) {
    __shared__ unsigned long long lm[PRE * 16];   // 128 KB
    __shared__ unsigned short keptIdx[POST];
    __shared__ int sTotal;
    int img = blockIdx.x;
    int t = threadIdx.x;
    const unsigned long long* mbase = masks + (size_t)img * PRE * 16;
    {
        const ulonglong2* src = (const ulonglong2*)mbase;
        ulonglong2* dst = (ulonglong2*)lm;
#pragma unroll
        for (int k = 0; k < 8; ++k) dst[t + k * 1024] = src[t + k * 1024];
    }
    __syncthreads();

    if (t < 64) {
        int lane = t;
        int lw = lane & 15;
        unsigned long long vmw = vmask[img * 16 + lw];
        unsigned long long supw = 0ULL;
        int cnt = 0;
        for (int b = 0; b < 16 && cnt < POST; ++b) {
            unsigned long long avail = readlane64(vmw, b) & ~readlane64(supw, b);
            while (avail && cnt < POST) {
                unsigned long long a = avail;
                int d0 = __ffsll((long long)a) - 1; a &= a - 1;
                int d1 = a ? __ffsll((long long)a) - 1 : 64; a &= a - 1;
                int d2 = a ? __ffsll((long long)a) - 1 : 64; a &= a - 1;
                int d3 = a ? __ffsll((long long)a) - 1 : 64; a &= a - 1;
                int r0 = b * 64 + d0;
                int r1 = b * 64 + (d1 & 63);
                int r2 = b * 64 + (d2 & 63);
                int r3 = b * 64 + (d3 & 63);
                unsigned long long w0 = lm[r0 * 16 + lw];
                unsigned long long w1 = lm[r1 * 16 + lw];
                unsigned long long w2 = lm[r2 * 16 + lw];
                unsigned long long w3 = lm[r3 * 16 + lw];
                unsigned long long sb = readlane64(w0, b);
                supw |= w0;
                if (lane == 0) keptIdx[cnt] = (unsigned short)r0;
                ++cnt;
                if (d1 < 64 && cnt < POST && !((sb >> d1) & 1ULL)) {
                    sb |= readlane64(w1, b); supw |= w1;
                    if (lane == 0) keptIdx[cnt] = (unsigned short)r1;
                    ++cnt;
                }
                if (d2 < 64 && cnt < POST && !((sb >> d2) & 1ULL)) {
                    sb |= readlane64(w2, b); supw |= w2;
                    if (lane == 0) keptIdx[cnt] = (unsigned short)r2;
                    ++cnt;
                }
                if (d3 < 64 && cnt < POST && !((sb >> d3) & 1ULL)) {
                    sb |= readlane64(w3, b); supw |= w3;
                    if (lane == 0) keptIdx[cnt] = (unsigned short)r3;
                    ++cnt;
                }
                avail = a & ~sb;
            }
        }
        if (lane == 0) sTotal = cnt;
    }
    __syncthreads();

    int total = sTotal;
    if (t < POST) {
        float v0 = 0.f, v1 = 0.f, v2 = 0.f, v3 = 0.f, v4 = 0.f, v5 = 0.f;
        if (t < total) {
            int i = keptIdx[t];
            const float* b = boxes + (size_t)(img * PRE + i) * 5;
            v0 = b[0]; v1 = b[1]; v2 = b[2]; v3 = b[3]; v4 = b[4];
            v5 = tscr[img * PRE + i];
        }
        float* o2 = out + (size_t)(img * POST + t) * 6;
        o2[0] = v0; o2[1] = v1; o2[2] = v2; o2[3] = v3; o2[4] = v4; o2[5] = v5;
    }
}

// ---------- workspace layout (16-byte aligned where vector-cast) ----------
enum : size_t {
    OFF_BOX  = 0,          // 2*1024*5*4  = 40960
    OFF_CORN = 40960,      // 2*1024*8*4  = 65536  -> 106496   (16-aligned, float4 reads)
    OFF_CIRC = 106496,     // 2*1024*16   = 32768  -> 139264   (float4)
    OFF_VMSK = 139264,     // 256                  -> 139520
    OFF_TSCR = 139520,     // 8192                 -> 147712
    OFF_MASK = 147712,     // 2*1024*16*8 = 262144 -> 409856   (16-aligned, ulonglong2 reads)
    OFF_HIST = 409856,     // 2*4096*4    = 32768  -> 442624
    OFF_CNTS = 442624,     // 32                   -> 442656
    OFF_SELB = 442656,     // 16                   -> 442672
    OFF_CBUF = 442672,     // 2*4096*8    = 65536  -> 508208
    OFF_SORT = 508208,     // 2*1024*8    = 16384  -> 524592
    OFF_PAIR = 524592,     // 131072*4    = 524288 -> 1048880
};

extern "C" void kernel_launch(void* const* d_in, const int* in_sizes, int n_in,
                              void* d_out, int out_size, void* d_ws, size_t ws_size,
                              hipStream_t stream) {
    const float* obj = (const float*)d_in[0];       // (2,1,256,256) f32
    const float* boxreg = (const float*)d_in[1];    // (2,5,256,256) f32
    float* out = (float*)d_out;                     // (2,256,6) f32

    char* w = (char*)d_ws;
    float* boxes = (float*)(w + OFF_BOX);
    float* corn = (float*)(w + OFF_CORN);
    float4* circ = (float4*)(w + OFF_CIRC);
    unsigned long long* vmask = (unsigned long long*)(w + OFF_VMSK);
    float* tscr = (float*)(w + OFF_TSCR);
    unsigned long long* masks = (unsigned long long*)(w + OFF_MASK);
    unsigned int* hist = (unsigned int*)(w + OFF_HIST);
    unsigned int* cnts = (unsigned int*)(w + OFF_CNTS);
    unsigned int* selB = (unsigned int*)(w + OFF_SELB);
    unsigned long long* cbuf = (unsigned long long*)(w + OFF_CBUF);
    unsigned long long* sorted = (unsigned long long*)(w + OFF_SORT);
    unsigned int* pairs = (unsigned int*)(w + OFF_PAIR);

    k_init<<<160, 256, 0, stream>>>(masks, hist, cnts);
    k_hista<<<16, 1024, 0, stream>>>(obj, hist);
    k_findbin<<<N_IMG, 256, 0, stream>>>(hist, selB);
    k_compact<<<64, 256, 0, stream>>>(obj, selB, cnts, cbuf);
    k_rank<<<32, 256, 0, stream>>>(cnts, cbuf, sorted);
    k_decode<<<16, 128, 0, stream>>>(sorted, boxreg, boxes, corn, circ, vmask, tscr);
    k_pairs<<<32, 256, 0, stream>>>(circ, cnts, pairs);
    k_clip<<<128, 256, 0, stream>>>(cnts, pairs, corn, circ, masks);
    k_nms_out<<<N_IMG, 1024, 0, stream>>>(masks, vmask, boxes, tscr, out);
}

// Round 11
// 90.107 us; speedup vs baseline: 2.5879x; 1.3638x over previous
//
#include <hip/hip_runtime.h>
#include <hip/hip_bf16.h>

#define N_IMG 2
#define HW 65536
#define PRE 1024
#define POST 256
#define NBIN 4096
#define SORTN 4096
#define PAIRCAP 131072
#define NMS_THR 0.7f
#define SCORE_T 0.1f
#define MIN_SZ 4.0f

// ---------- sortable key helpers ----------
__device__ __forceinline__ unsigned int fkey(float f) {
    unsigned int u = __float_as_uint(f);
    return u ^ ((u & 0x80000000u) ? 0xFFFFFFFFu : 0x80000000u);
}
__device__ __forceinline__ float unfkey(unsigned int k) {
    unsigned int u = (k & 0x80000000u) ? (k ^ 0x80000000u) : ~k;
    return __uint_as_float(u);
}
__device__ __forceinline__ unsigned long long readlane64(unsigned long long v, int l) {
    unsigned int lo = (unsigned int)__builtin_amdgcn_readlane((int)(unsigned int)v, l);
    unsigned int hi = (unsigned int)__builtin_amdgcn_readlane((int)(unsigned int)(v >> 32), l);
    return ((unsigned long long)hi << 32) | (unsigned long long)lo;
}

// ============================================================================
// K0: zero masks / hist / counters
// ============================================================================
__global__ void k_init(unsigned long long* masks, unsigned int* hist, unsigned int* cnts) {
    int t = blockIdx.x * blockDim.x + threadIdx.x;        // 160*256 = 40960
    if (t < N_IMG * PRE * 16) masks[t] = 0ULL;            // 32768 words
    if (t < N_IMG * NBIN) hist[t] = 0u;
    if (t < 8) cnts[t] = 0u;                              // [0..1]=cand cnt, [2]=pair cnt
}

// ============================================================================
// K1: 12-bit-prefix histogram — per-block LDS hist, sparse global merge.
// ============================================================================
__global__ __launch_bounds__(1024) void k_hista(const float* __restrict__ obj,
                                                unsigned int* hist) {
    __shared__ unsigned int lh[NBIN];
    int img = blockIdx.x >> 3;                            // 8 blocks per image
    int seg = blockIdx.x & 7;
    for (int i = threadIdx.x; i < NBIN; i += 1024) lh[i] = 0u;
    __syncthreads();
    const float4* o4 = (const float4*)(obj + (size_t)img * HW);
    int base = seg * 2048;                                // 2048 float4 per segment
#pragma unroll
    for (int k = 0; k < 2; ++k) {
        float4 v = o4[base + threadIdx.x + k * 1024];
        atomicAdd(&lh[fkey(v.x) >> 20], 1u);
        atomicAdd(&lh[fkey(v.y) >> 20], 1u);
        atomicAdd(&lh[fkey(v.z) >> 20], 1u);
        atomicAdd(&lh[fkey(v.w) >> 20], 1u);
    }
    __syncthreads();
    for (int i = threadIdx.x; i < NBIN; i += 1024) {
        unsigned int c = lh[i];
        if (c) atomicAdd(&hist[img * NBIN + i], c);       // ~200 nonzero bins/block
    }
}

// ============================================================================
// K2: find threshold bin (proven R0-R3 logic, global hist)
// ============================================================================
__global__ void k_findbin(const unsigned int* __restrict__ hist, unsigned int* selB) {
    __shared__ unsigned int lh[NBIN];
    __shared__ unsigned int chunk[256];
    int img = blockIdx.x;
    int t = threadIdx.x;
    unsigned int s = 0;
    for (int k = 0; k < 16; ++k) {
        unsigned int v = hist[img * NBIN + t * 16 + k];
        lh[t * 16 + k] = v;
        s += v;
    }
    chunk[t] = s;
    __syncthreads();
    if (t == 0) {
        unsigned int run = 0;
        int c;
        for (c = 255; c >= 0; --c) {
            if (run + chunk[c] >= PRE) break;
            run += chunk[c];
        }
        unsigned int B = 0;
        for (int b = c * 16 + 15; b >= c * 16; --b) {
            if (run + lh[b] >= PRE) { B = (unsigned int)b; break; }
            run += lh[b];
        }
        selB[img] = B;
    }
}

// ============================================================================
// K3: compact candidates — block-LDS aggregation, ONE global atomic per
// block per image.
// ============================================================================
__global__ __launch_bounds__(256) void k_compact(const float* __restrict__ obj,
                                                 const unsigned int* __restrict__ selB,
                                                 unsigned int* cnts, unsigned long long* cbuf) {
    __shared__ unsigned long long lbuf[1024];             // max 256 thr x 4 elems
    __shared__ unsigned int lcnt, lbase;
    int t = blockIdx.x * 256 + threadIdx.x;               // 0..16383
    const float4* o4 = (const float4*)obj;
#pragma unroll
    for (int k = 0; k < 2; ++k) {
        if (threadIdx.x == 0) lcnt = 0;
        __syncthreads();
        int p = t + k * 16384;                            // img = k (uniform)
        int img = p >> 14;
        unsigned int B = selB[img];
        float4 v = o4[p];
        float vs[4] = {v.x, v.y, v.z, v.w};
#pragma unroll
        for (int c = 0; c < 4; ++c) {
            unsigned int key = fkey(vs[c]);
            if ((key >> 20) >= B) {
                unsigned int i = (unsigned int)((p & 16383) * 4 + c);   // elem within image
                unsigned int pos = atomicAdd(&lcnt, 1u);                // LDS atomic
                lbuf[pos] = ((unsigned long long)key << 32) |
                            (unsigned long long)(0xFFFFFFFFu - i);
            }
        }
        __syncthreads();
        if (threadIdx.x == 0) lbase = atomicAdd(&cnts[img], lcnt);      // 1 global atomic
        __syncthreads();
        unsigned int n = lcnt, base = lbase;
        for (unsigned int q = threadIdx.x; q < n; q += 256) {
            unsigned int gp = base + q;
            if (gp < SORTN) cbuf[img * SORTN + gp] = lbuf[q];
        }
        __syncthreads();                                  // protect lcnt reuse
    }
}

// ============================================================================
// K4: counting-rank sort (order-independent -> deterministic), 32 blocks
// ============================================================================
__global__ __launch_bounds__(256) void k_rank(const unsigned int* __restrict__ cnts,
                                              const unsigned long long* __restrict__ cbuf,
                                              unsigned long long* sorted) {
    __shared__ unsigned long long keys[SORTN];            // 32 KB
    int img = blockIdx.x >> 4;                            // 16 slices per image
    int slice = blockIdx.x & 15;
    unsigned int M = cnts[img]; if (M > SORTN) M = SORTN;
    for (unsigned int i = threadIdx.x; i < M; i += 256) keys[i] = cbuf[img * SORTN + i];
    __syncthreads();
    unsigned int cid = (unsigned int)slice * 256 + threadIdx.x;
    if (cid < M) {
        unsigned long long c = keys[cid];
        unsigned int r = 0;
        for (unsigned int j = 0; j < M; ++j) r += (keys[j] > c) ? 1u : 0u;
        if (r < PRE) sorted[img * PRE + r] = c;           // keys unique -> ranks unique
    }
}

// ============================================================================
// K5: decode top-1024, wide (16 blocks x 128)
// ============================================================================
__global__ __launch_bounds__(128) void k_decode(const unsigned long long* __restrict__ sorted,
                                                const float* __restrict__ boxreg,
                                                float* boxes, float* corn, float4* circ,
                                                unsigned long long* vmask, float* tscr) {
    int g = blockIdx.x * 128 + threadIdx.x;               // 0..2047
    int img = g >> 10;
    int t = g & 1023;
    unsigned long long v = sorted[g];
    unsigned int key = (unsigned int)(v >> 32);
    unsigned int idx = (0xFFFFFFFFu - (unsigned int)(v & 0xFFFFFFFFULL)) & 0xFFFFu;
    float sc = unfkey(key);
    int h = (int)(idx >> 8);
    int w = (int)(idx & 255u);
    const float* rg = boxreg + (size_t)img * 5 * HW;
    float t_ = rg[0 * HW + idx] * 1024.0f;
    float rr = rg[1 * HW + idx] * 1024.0f;
    float bb = rg[2 * HW + idx] * 1024.0f;
    float ll = rg[3 * HW + idx] * 1024.0f;
    float ang = (rg[4 * HW + idx] - 0.5f) * 90.0f;
    float wd = ll + rr;
    float ht = t_ + bb;
    float xc = (float)w * 4.0f + 0.5f * (rr - ll);
    float yc = (float)h * 4.0f + 0.5f * (bb - t_);
    xc = fminf(fmaxf(xc, 0.0f), 1023.0f);
    yc = fminf(fmaxf(yc, 0.0f), 1023.0f);
    bool valid = (sc > SCORE_T) && (wd >= MIN_SZ) && (ht >= MIN_SZ);

    float* bx = boxes + (size_t)g * 5;
    bx[0] = xc; bx[1] = yc; bx[2] = wd; bx[3] = ht; bx[4] = ang;
    tscr[g] = sc;

    float th = ang * (float)(3.14159265358979323846 / 180.0);
    float c = cosf(th), s = sinf(th);
    const float dxs[4] = {-0.5f, 0.5f, 0.5f, -0.5f};
    const float dys[4] = {-0.5f, -0.5f, 0.5f, 0.5f};
    float* cr = corn + (size_t)g * 8;
#pragma unroll
    for (int k = 0; k < 4; ++k) {
        float dx = dxs[k] * wd, dy = dys[k] * ht;
        cr[2 * k]     = xc + dx * c - dy * s;
        cr[2 * k + 1] = yc + dx * s + dy * c;
    }
    circ[g] = make_float4(xc, yc, 0.5f * sqrtf(wd * wd + ht * ht) + 0.01f, wd * ht);

    unsigned long long bal = __ballot(valid ? 1 : 0);
    if ((t & 63) == 0) vmask[img * 16 + (t >> 6)] = bal;  // blocks don't straddle images
}

// ============================================================================
// K6: circle-prune pair enumeration, WIDE (R8 form: 512 blocks x 16 short
// iters, global circ reads hit L1/L2 — don't stage what already cache-fits).
// Block-LDS compaction -> one global bump per block.
// ============================================================================
__global__ __launch_bounds__(256) void k_pairs(const float4* __restrict__ circ,
                                               unsigned int* cnts, unsigned int* pairs) {
    __shared__ unsigned int lbuf[1024];
    __shared__ unsigned int lcnt, lbase;
    if (threadIdx.x == 0) lcnt = 0;
    __syncthreads();
    int t0 = blockIdx.x * 256 + threadIdx.x;              // 131072 threads
#pragma unroll
    for (int k = 0; k < 16; ++k) {
        int p = t0 + k * 131072;                          // 2*1024*1024 pairs
        int img = p >> 20;
        int r = p & 1048575;
        int i = r >> 10, j = r & 1023;
        if (j > i) {
            float4 a = circ[img * PRE + i];
            float4 b = circ[img * PRE + j];
            float dx = b.x - a.x, dy = b.y - a.y, rr = a.z + b.z;
            if (dx * dx + dy * dy <= rr * rr) {
                unsigned int pr = ((unsigned int)img << 20) | ((unsigned int)i << 10) | (unsigned int)j;
                unsigned int pos = atomicAdd(&lcnt, 1u);
                if (pos < 1024) lbuf[pos] = pr;
                else {
                    unsigned int gp = atomicAdd(&cnts[2], 1u);
                    if (gp < PAIRCAP) pairs[gp] = pr;
                }
            }
        }
    }
    __syncthreads();
    unsigned int n = lcnt; if (n > 1024) n = 1024;
    if (threadIdx.x == 0) lbase = atomicAdd(&cnts[2], n);
    __syncthreads();
    unsigned int base = lbase;
    for (unsigned int q = threadIdx.x; q < n; q += 256) {
        unsigned int gp = base + q;
        if (gp < PAIRCAP) pairs[gp] = lbuf[q];
    }
}

// ============================================================================
// K7: dense Sutherland-Hodgman clip per surviving pair; LDS [slot][tid] scratch
// ============================================================================
__global__ __launch_bounds__(256) void k_clip(const unsigned int* __restrict__ cnts,
                                              const unsigned int* __restrict__ pairs,
                                              const float* __restrict__ corn,
                                              const float4* __restrict__ circ,
                                              unsigned long long* masks) {
    __shared__ float SPX[8][256], SPY[8][256], SQX[8][256], SQY[8][256];   // 32 KB
    int tid = threadIdx.x;
    unsigned int total = cnts[2]; if (total > PAIRCAP) total = PAIRCAP;
    for (unsigned int p = blockIdx.x * 256 + tid; p < total; p += 128 * 256) {
        unsigned int pr = pairs[p];
        int img = (int)(pr >> 20);
        int i = (int)((pr >> 10) & 1023);
        int j = (int)(pr & 1023);
        int ra = img * PRE + i, rb = img * PRE + j;
        const float4* ca = (const float4*)(corn + (size_t)ra * 8);
        float4 a0 = ca[0], a1 = ca[1];
        const float4* cb = (const float4*)(corn + (size_t)rb * 8);
        float4 b0 = cb[0], b1 = cb[1];
        float cbx[4] = {b0.x, b0.z, b1.x, b1.z};
        float cby[4] = {b0.y, b0.w, b1.y, b1.w};
        SPX[0][tid] = a0.x; SPY[0][tid] = a0.y;
        SPX[1][tid] = a0.z; SPY[1][tid] = a0.w;
        SPX[2][tid] = a1.x; SPY[2][tid] = a1.y;
        SPX[3][tid] = a1.z; SPY[3][tid] = a1.w;
        int n = 4;
#pragma unroll
        for (int e = 0; e < 4; ++e) {
            float (*PX)[256] = (e & 1) ? SQX : SPX;       // static after unroll
            float (*PY)[256] = (e & 1) ? SQY : SPY;
            float (*QX)[256] = (e & 1) ? SPX : SQX;
            float (*QY)[256] = (e & 1) ? SPY : SQY;
            float p1x = cbx[e], p1y = cby[e];
            int e2 = (e + 1) & 3;
            float ex = cbx[e2] - p1x, ey = cby[e2] - p1y;
            int m = 0;
            for (int k = 0; k < n; ++k) {
                int kn = (k + 1 < n) ? k + 1 : 0;
                float cx_ = PX[k][tid], cy_ = PY[k][tid];
                float nx_ = PX[kn][tid], ny_ = PY[kn][tid];
                float dc = ex * (cy_ - p1y) - ey * (cx_ - p1x);
                float dn = ex * (ny_ - p1y) - ey * (nx_ - p1x);
                bool ic = dc >= 0.0f;
                bool inx = dn >= 0.0f;
                if (ic && m < 8) { QX[m][tid] = cx_; QY[m][tid] = cy_; ++m; }
                if ((ic != inx) && m < 8) {
                    float den = dc - dn;
                    float safe = (fabsf(den) > 1e-9f) ? den : 1.0f;
                    float tt = dc / safe;
                    QX[m][tid] = cx_ + tt * (nx_ - cx_);
                    QY[m][tid] = cy_ + tt * (ny_ - cy_);
                    ++m;
                }
            }
            n = m;
        }
        // e=0:P->Q, e=1:Q->P, e=2:P->Q, e=3:Q->P  => final polygon in SPX/SPY
        float inter = 0.0f;
        if (n >= 3) {
            float s = 0.0f;
            for (int k = 0; k < n; ++k) {
                int kn = (k + 1 < n) ? k + 1 : 0;
                s += SPX[k][tid] * SPY[kn][tid] - SPX[kn][tid] * SPY[k][tid];
            }
            inter = 0.5f * fabsf(s);
        }
        float uni = circ[ra].w + circ[rb].w - inter;
        float iou = inter / fmaxf(uni, 1e-9f);
        if (iou > NMS_THR)
            atomicOr(&masks[(size_t)ra * 16 + (j >> 6)], 1ULL << (j & 63));
    }
}

// ============================================================================
// K8: greedy NMS (LDS-staged masks, early-stop, batch-4) + output
// ============================================================================
__global__ __launch_bounds__(1024) void k_nms_out(const unsigned long long* __restrict__ masks,
                                                  const unsigned long long* __restrict__ vmask,
                                                  const float* __restrict__ boxes,
                                                  const float* __restrict__ tscr,
                                                  float* __restrict__ out) {
    __shared__ unsigned long long lm[PRE * 16];   // 128 KB
    __shared__ unsigned short keptIdx[POST];
    __shared__ int sTotal;
    int img = blockIdx.x;
    int t = threadIdx.x;
    const unsigned long long* mbase = masks + (size_t)img * PRE * 16;
    {
        const ulonglong2* src = (const ulonglong2*)mbase;
        ulonglong2* dst = (ulonglong2*)lm;
#pragma unroll
        for (int k = 0; k < 8; ++k) dst[t + k * 1024] = src[t + k * 1024];
    }
    __syncthreads();

    if (t < 64) {
        int lane = t;
        int lw = lane & 15;
        unsigned long long vmw = vmask[img * 16 + lw];
        unsigned long long supw = 0ULL;
        int cnt = 0;
        for (int b = 0; b < 16 && cnt < POST; ++b) {
            unsigned long long avail = readlane64(vmw, b) & ~readlane64(supw, b);
            while (avail && cnt < POST) {
                unsigned long long a = avail;
                int d0 = __ffsll((long long)a) - 1; a &= a - 1;
                int d1 = a ? __ffsll((long long)a) - 1 : 64; a &= a - 1;
                int d2 = a ? __ffsll((long long)a) - 1 : 64; a &= a - 1;
                int d3 = a ? __ffsll((long long)a) - 1 : 64; a &= a - 1;
                int r0 = b * 64 + d0;
                int r1 = b * 64 + (d1 & 63);
                int r2 = b * 64 + (d2 & 63);
                int r3 = b * 64 + (d3 & 63);
                unsigned long long w0 = lm[r0 * 16 + lw];
                unsigned long long w1 = lm[r1 * 16 + lw];
                unsigned long long w2 = lm[r2 * 16 + lw];
                unsigned long long w3 = lm[r3 * 16 + lw];
                unsigned long long sb = readlane64(w0, b);
                supw |= w0;
                if (lane == 0) keptIdx[cnt] = (unsigned short)r0;
                ++cnt;
                if (d1 < 64 && cnt < POST && !((sb >> d1) & 1ULL)) {
                    sb |= readlane64(w1, b); supw |= w1;
                    if (lane == 0) keptIdx[cnt] = (unsigned short)r1;
                    ++cnt;
                }
                if (d2 < 64 && cnt < POST && !((sb >> d2) & 1ULL)) {
                    sb |= readlane64(w2, b); supw |= w2;
                    if (lane == 0) keptIdx[cnt] = (unsigned short)r2;
                    ++cnt;
                }
                if (d3 < 64 && cnt < POST && !((sb >> d3) & 1ULL)) {
                    sb |= readlane64(w3, b); supw |= w3;
                    if (lane == 0) keptIdx[cnt] = (unsigned short)r3;
                    ++cnt;
                }
                avail = a & ~sb;
            }
        }
        if (lane == 0) sTotal = cnt;
    }
    __syncthreads();

    int total = sTotal;
    if (t < POST) {
        float v0 = 0.f, v1 = 0.f, v2 = 0.f, v3 = 0.f, v4 = 0.f, v5 = 0.f;
        if (t < total) {
            int i = keptIdx[t];
            const float* b = boxes + (size_t)(img * PRE + i) * 5;
            v0 = b[0]; v1 = b[1]; v2 = b[2]; v3 = b[3]; v4 = b[4];
            v5 = tscr[img * PRE + i];
        }
        float* o2 = out + (size_t)(img * POST + t) * 6;
        o2[0] = v0; o2[1] = v1; o2[2] = v2; o2[3] = v3; o2[4] = v4; o2[5] = v5;
    }
}

// ---------- workspace layout (16-byte aligned where vector-cast) ----------
enum : size_t {
    OFF_BOX  = 0,          // 2*1024*5*4  = 40960
    OFF_CORN = 40960,      // 2*1024*8*4  = 65536  -> 106496   (16-aligned, float4 reads)
    OFF_CIRC = 106496,     // 2*1024*16   = 32768  -> 139264   (float4)
    OFF_VMSK = 139264,     // 256                  -> 139520
    OFF_TSCR = 139520,     // 8192                 -> 147712
    OFF_MASK = 147712,     // 2*1024*16*8 = 262144 -> 409856   (16-aligned, ulonglong2 reads)
    OFF_HIST = 409856,     // 2*4096*4    = 32768  -> 442624
    OFF_CNTS = 442624,     // 32                   -> 442656
    OFF_SELB = 442656,     // 16                   -> 442672
    OFF_CBUF = 442672,     // 2*4096*8    = 65536  -> 508208
    OFF_SORT = 508208,     // 2*1024*8    = 16384  -> 524592
    OFF_PAIR = 524592,     // 131072*4    = 524288 -> 1048880
};

extern "C" void kernel_launch(void* const* d_in, const int* in_sizes, int n_in,
                              void* d_out, int out_size, void* d_ws, size_t ws_size,
                              hipStream_t stream) {
    const float* obj = (const float*)d_in[0];       // (2,1,256,256) f32
    const float* boxreg = (const float*)d_in[1];    // (2,5,256,256) f32
    float* out = (float*)d_out;                     // (2,256,6) f32

    char* w = (char*)d_ws;
    float* boxes = (float*)(w + OFF_BOX);
    float* corn = (float*)(w + OFF_CORN);
    float4* circ = (float4*)(w + OFF_CIRC);
    unsigned long long* vmask = (unsigned long long*)(w + OFF_VMSK);
    float* tscr = (float*)(w + OFF_TSCR);
    unsigned long long* masks = (unsigned long long*)(w + OFF_MASK);
    unsigned int* hist = (unsigned int*)(w + OFF_HIST);
    unsigned int* cnts = (unsigned int*)(w + OFF_CNTS);
    unsigned int* selB = (unsigned int*)(w + OFF_SELB);
    unsigned long long* cbuf = (unsigned long long*)(w + OFF_CBUF);
    unsigned long long* sorted = (unsigned long long*)(w + OFF_SORT);
    unsigned int* pairs = (unsigned int*)(w + OFF_PAIR);

    k_init<<<160, 256, 0, stream>>>(masks, hist, cnts);
    k_hista<<<16, 1024, 0, stream>>>(obj, hist);
    k_findbin<<<N_IMG, 256, 0, stream>>>(hist, selB);
    k_compact<<<64, 256, 0, stream>>>(obj, selB, cnts, cbuf);
    k_rank<<<32, 256, 0, stream>>>(cnts, cbuf, sorted);
    k_decode<<<16, 128, 0, stream>>>(sorted, boxreg, boxes, corn, circ, vmask, tscr);
    k_pairs<<<512, 256, 0, stream>>>(circ, cnts, pairs);
    k_clip<<<128, 256, 0, stream>>>(cnts, pairs, corn, circ, masks);
    k_nms_out<<<N_IMG, 1024, 0, stream>>>(masks, vmask, boxes, tscr, out);
}

// Round 12
// 88.774 us; speedup vs baseline: 2.6267x; 1.0150x over previous
//
#include <hip/hip_runtime.h>
#include <hip/hip_bf16.h>

#define N_IMG 2
#define HW 65536
#define PRE 1024
#define POST 256
#define NBIN 4096
#define SORTN 4096
#define NMS_THR 0.7f
#define SCORE_T 0.1f
#define MIN_SZ 4.0f

// ---------- helpers ----------
__device__ __forceinline__ unsigned int fkey(float f) {
    unsigned int u = __float_as_uint(f);
    return u ^ ((u & 0x80000000u) ? 0xFFFFFFFFu : 0x80000000u);
}
__device__ __forceinline__ float unfkey(unsigned int k) {
    unsigned int u = (k & 0x80000000u) ? (k ^ 0x80000000u) : ~k;
    return __uint_as_float(u);
}
__device__ __forceinline__ unsigned long long readlane64(unsigned long long v, int l) {
    unsigned int lo = (unsigned int)__builtin_amdgcn_readlane((int)(unsigned int)v, l);
    unsigned int hi = (unsigned int)__builtin_amdgcn_readlane((int)(unsigned int)(v >> 32), l);
    return ((unsigned long long)hi << 32) | (unsigned long long)lo;
}

// ============================================================================
// K1 (fused init+hist): zero masks/cnts; per-block LDS histogram -> PRIVATE
// partial-hist region (plain stores; no global atomics, no pre-zeroed hist).
// 16 blocks x 1024: blockIdx = img*8 + seg.
// ============================================================================
__global__ __launch_bounds__(1024) void k_front(const float* __restrict__ obj,
                                                unsigned int* phist,
                                                unsigned long long* masks,
                                                unsigned int* cnts) {
    __shared__ unsigned int lh[NBIN];
    int img = blockIdx.x >> 3;
    int seg = blockIdx.x & 7;
    for (int i = threadIdx.x; i < NBIN; i += 1024) lh[i] = 0u;
    {   // zero masks: 32768 words / 16 blocks = 2048 words per block
        unsigned long long* mz = masks + (size_t)blockIdx.x * 2048;
        mz[threadIdx.x] = 0ULL;
        mz[threadIdx.x + 1024] = 0ULL;
    }
    if (blockIdx.x == 0 && threadIdx.x < 8) cnts[threadIdx.x] = 0u;
    __syncthreads();
    const float4* o4 = (const float4*)(obj + (size_t)img * HW);
    int base = seg * 2048;                                // 2048 float4 per segment
#pragma unroll
    for (int k = 0; k < 2; ++k) {
        float4 v = o4[base + threadIdx.x + k * 1024];
        atomicAdd(&lh[fkey(v.x) >> 20], 1u);
        atomicAdd(&lh[fkey(v.y) >> 20], 1u);
        atomicAdd(&lh[fkey(v.z) >> 20], 1u);
        atomicAdd(&lh[fkey(v.w) >> 20], 1u);
    }
    __syncthreads();
    unsigned int* ph = phist + (size_t)blockIdx.x * NBIN;
    for (int i = threadIdx.x; i < NBIN; i += 1024) ph[i] = lh[i];
}

// ============================================================================
// K2: find threshold bin — sums the 8 partials per image (coalesced), then
// the proven serial scan.
// ============================================================================
__global__ void k_findbin(const unsigned int* __restrict__ phist, unsigned int* selB) {
    __shared__ unsigned int lh[NBIN];
    __shared__ unsigned int chunk[256];
    int img = blockIdx.x;
    int t = threadIdx.x;
    for (int c = 0; c < 16; ++c) {                        // coalesced: bin = c*256+t
        int b = c * 256 + t;
        unsigned int v = 0;
#pragma unroll
        for (int q = 0; q < 8; ++q) v += phist[(size_t)(img * 8 + q) * NBIN + b];
        lh[b] = v;
    }
    __syncthreads();
    unsigned int s = 0;
    for (int k = 0; k < 16; ++k) s += lh[t * 16 + k];
    chunk[t] = s;
    __syncthreads();
    if (t == 0) {
        unsigned int run = 0;
        int c;
        for (c = 255; c >= 0; --c) {
            if (run + chunk[c] >= PRE) break;
            run += chunk[c];
        }
        unsigned int B = 0;
        for (int b = c * 16 + 15; b >= c * 16; --b) {
            if (run + lh[b] >= PRE) { B = (unsigned int)b; break; }
            run += lh[b];
        }
        selB[img] = B;
    }
}

// ============================================================================
// K3: compact candidates — block-LDS aggregation, ONE global atomic per
// block per image. (proven R10)
// ============================================================================
__global__ __launch_bounds__(256) void k_compact(const float* __restrict__ obj,
                                                 const unsigned int* __restrict__ selB,
                                                 unsigned int* cnts, unsigned long long* cbuf) {
    __shared__ unsigned long long lbuf[1024];             // max 256 thr x 4 elems
    __shared__ unsigned int lcnt, lbase;
    int t = blockIdx.x * 256 + threadIdx.x;               // 0..16383
    const float4* o4 = (const float4*)obj;
#pragma unroll
    for (int k = 0; k < 2; ++k) {
        if (threadIdx.x == 0) lcnt = 0;
        __syncthreads();
        int p = t + k * 16384;                            // img = k (uniform)
        int img = p >> 14;
        unsigned int B = selB[img];
        float4 v = o4[p];
        float vs[4] = {v.x, v.y, v.z, v.w};
#pragma unroll
        for (int c = 0; c < 4; ++c) {
            unsigned int key = fkey(vs[c]);
            if ((key >> 20) >= B) {
                unsigned int i = (unsigned int)((p & 16383) * 4 + c);   // elem within image
                unsigned int pos = atomicAdd(&lcnt, 1u);                // LDS atomic
                lbuf[pos] = ((unsigned long long)key << 32) |
                            (unsigned long long)(0xFFFFFFFFu - i);
            }
        }
        __syncthreads();
        if (threadIdx.x == 0) lbase = atomicAdd(&cnts[img], lcnt);      // 1 global atomic
        __syncthreads();
        unsigned int n = lcnt, base = lbase;
        for (unsigned int q = threadIdx.x; q < n; q += 256) {
            unsigned int gp = base + q;
            if (gp < SORTN) cbuf[img * SORTN + gp] = lbuf[q];
        }
        __syncthreads();                                  // protect lcnt reuse
    }
}

// ============================================================================
// K4 (fused rank+decode): counting-rank (deterministic, keys unique); the
// thread holding rank r < PRE decodes its candidate inline. Validity -> varr.
// 32 blocks x 256.
// ============================================================================
__global__ __launch_bounds__(256) void k_rankdec(const unsigned int* __restrict__ cnts,
                                                 const unsigned long long* __restrict__ cbuf,
                                                 const float* __restrict__ boxreg,
                                                 float* boxes, float* corn, float4* circ,
                                                 unsigned int* varr, float* tscr) {
    __shared__ unsigned long long keys[SORTN];            // 32 KB
    int img = blockIdx.x >> 4;                            // 16 slices per image
    int slice = blockIdx.x & 15;
    unsigned int M = cnts[img]; if (M > SORTN) M = SORTN;
    for (unsigned int i = threadIdx.x; i < M; i += 256) keys[i] = cbuf[img * SORTN + i];
    __syncthreads();
    unsigned int cid = (unsigned int)slice * 256 + threadIdx.x;
    if (cid >= M) return;
    unsigned long long cv = keys[cid];
    unsigned int r = 0;
    for (unsigned int j = 0; j < M; ++j) r += (keys[j] > cv) ? 1u : 0u;
    if (r >= PRE) return;

    int g = img * PRE + (int)r;
    unsigned int key = (unsigned int)(cv >> 32);
    unsigned int idx = (0xFFFFFFFFu - (unsigned int)(cv & 0xFFFFFFFFULL)) & 0xFFFFu;
    float sc = unfkey(key);
    int h = (int)(idx >> 8);
    int w = (int)(idx & 255u);
    const float* rg = boxreg + (size_t)img * 5 * HW;
    float t_ = rg[0 * HW + idx] * 1024.0f;
    float rr = rg[1 * HW + idx] * 1024.0f;
    float bb = rg[2 * HW + idx] * 1024.0f;
    float ll = rg[3 * HW + idx] * 1024.0f;
    float ang = (rg[4 * HW + idx] - 0.5f) * 90.0f;
    float wd = ll + rr;
    float ht = t_ + bb;
    float xc = (float)w * 4.0f + 0.5f * (rr - ll);
    float yc = (float)h * 4.0f + 0.5f * (bb - t_);
    xc = fminf(fmaxf(xc, 0.0f), 1023.0f);
    yc = fminf(fmaxf(yc, 0.0f), 1023.0f);
    bool valid = (sc > SCORE_T) && (wd >= MIN_SZ) && (ht >= MIN_SZ);

    float* bx = boxes + (size_t)g * 5;
    bx[0] = xc; bx[1] = yc; bx[2] = wd; bx[3] = ht; bx[4] = ang;
    tscr[g] = sc;
    varr[g] = valid ? 1u : 0u;

    float th = ang * (float)(3.14159265358979323846 / 180.0);
    float c = cosf(th), s = sinf(th);
    const float dxs[4] = {-0.5f, 0.5f, 0.5f, -0.5f};
    const float dys[4] = {-0.5f, -0.5f, 0.5f, 0.5f};
    float* cr = corn + (size_t)g * 8;
#pragma unroll
    for (int k = 0; k < 4; ++k) {
        float dx = dxs[k] * wd, dy = dys[k] * ht;
        cr[2 * k]     = xc + dx * c - dy * s;
        cr[2 * k + 1] = yc + dx * s + dy * c;
    }
    circ[g] = make_float4(xc, yc, 0.5f * sqrtf(wd * wd + ht * ht) + 0.01f, wd * ht);
}

// ============================================================================
// K5 (fused pairs+clip): 512 blocks enumerate circle-passing pairs into a
// block-local LDS list; drain through the [slot][tid] clip scratch when the
// list nears capacity or at the end. atomicOr into zeroed masks. No global
// pair buffer, no capacity drop.
// ============================================================================
__global__ __launch_bounds__(256) void k_pairclip(const float4* __restrict__ circ,
                                                  const float* __restrict__ corn,
                                                  unsigned long long* masks) {
    __shared__ float SPX[8][256], SPY[8][256], SQX[8][256], SQY[8][256];   // 32 KB
    __shared__ unsigned int plist[1280];                  // 1024 cap + 256 headroom
    __shared__ unsigned int pcnt;
    int tid = threadIdx.x;
    if (tid == 0) pcnt = 0;
    __syncthreads();
    int t0 = blockIdx.x * 256 + tid;                      // 131072 threads
    for (int k = 0; k < 16; ++k) {
        int p = t0 + k * 131072;                          // 2*1024*1024 pairs
        int img = p >> 20;
        int r = p & 1048575;
        int i = r >> 10, j = r & 1023;
        if (j > i) {
            float4 a = circ[img * PRE + i];
            float4 b = circ[img * PRE + j];
            float dx = b.x - a.x, dy = b.y - a.y, rr = a.z + b.z;
            if (dx * dx + dy * dy <= rr * rr)
                plist[atomicAdd(&pcnt, 1u)] =
                    ((unsigned int)img << 20) | ((unsigned int)i << 10) | (unsigned int)j;
        }
        __syncthreads();
        unsigned int n = pcnt;                            // uniform
        if (n >= 1024 || k == 15) {
            for (unsigned int q = tid; q < n; q += 256) {
                unsigned int pr = plist[q];
                int im = (int)(pr >> 20);
                int bi = (int)((pr >> 10) & 1023);
                int bj = (int)(pr & 1023);
                int ra = im * PRE + bi, rb = im * PRE + bj;
                const float4* ca = (const float4*)(corn + (size_t)ra * 8);
                float4 a0 = ca[0], a1 = ca[1];
                const float4* cb = (const float4*)(corn + (size_t)rb * 8);
                float4 b0 = cb[0], b1 = cb[1];
                float cbx[4] = {b0.x, b0.z, b1.x, b1.z};
                float cby[4] = {b0.y, b0.w, b1.y, b1.w};
                SPX[0][tid] = a0.x; SPY[0][tid] = a0.y;
                SPX[1][tid] = a0.z; SPY[1][tid] = a0.w;
                SPX[2][tid] = a1.x; SPY[2][tid] = a1.y;
                SPX[3][tid] = a1.z; SPY[3][tid] = a1.w;
                int n2 = 4;
#pragma unroll
                for (int e = 0; e < 4; ++e) {
                    float (*PX)[256] = (e & 1) ? SQX : SPX;
                    float (*PY)[256] = (e & 1) ? SQY : SPY;
                    float (*QX)[256] = (e & 1) ? SPX : SQX;
                    float (*QY)[256] = (e & 1) ? SPY : SQY;
                    float p1x = cbx[e], p1y = cby[e];
                    int e2 = (e + 1) & 3;
                    float ex = cbx[e2] - p1x, ey = cby[e2] - p1y;
                    int m = 0;
                    for (int kk = 0; kk < n2; ++kk) {
                        int kn = (kk + 1 < n2) ? kk + 1 : 0;
                        float cx_ = PX[kk][tid], cy_ = PY[kk][tid];
                        float nx_ = PX[kn][tid], ny_ = PY[kn][tid];
                        float dc = ex * (cy_ - p1y) - ey * (cx_ - p1x);
                        float dn = ex * (ny_ - p1y) - ey * (nx_ - p1x);
                        bool ic = dc >= 0.0f;
                        bool inx = dn >= 0.0f;
                        if (ic && m < 8) { QX[m][tid] = cx_; QY[m][tid] = cy_; ++m; }
                        if ((ic != inx) && m < 8) {
                            float den = dc - dn;
                            float safe = (fabsf(den) > 1e-9f) ? den : 1.0f;
                            float tt = dc / safe;
                            QX[m][tid] = cx_ + tt * (nx_ - cx_);
                            QY[m][tid] = cy_ + tt * (ny_ - cy_);
                            ++m;
                        }
                    }
                    n2 = m;
                }
                float inter = 0.0f;
                if (n2 >= 3) {
                    float s = 0.0f;
                    for (int kk = 0; kk < n2; ++kk) {
                        int kn = (kk + 1 < n2) ? kk + 1 : 0;
                        s += SPX[kk][tid] * SPY[kn][tid] - SPX[kn][tid] * SPY[kk][tid];
                    }
                    inter = 0.5f * fabsf(s);
                }
                float uni = circ[ra].w + circ[rb].w - inter;
                float iou = inter / fmaxf(uni, 1e-9f);
                if (iou > NMS_THR)
                    atomicOr(&masks[(size_t)ra * 16 + (bj >> 6)], 1ULL << (bj & 63));
            }
            __syncthreads();
            if (tid == 0) pcnt = 0;
            __syncthreads();
        }
    }
}

// ============================================================================
// K6: greedy NMS + output. Builds vmask from varr via per-wave ballots, then
// the proven LDS skip-scan (early-stop @POST, batch-4 speculative reads).
// ============================================================================
__global__ __launch_bounds__(1024) void k_nms_out(const unsigned long long* __restrict__ masks,
                                                  const unsigned int* __restrict__ varr,
                                                  const float* __restrict__ boxes,
                                                  const float* __restrict__ tscr,
                                                  float* __restrict__ out) {
    __shared__ unsigned long long lm[PRE * 16];   // 128 KB
    __shared__ unsigned long long vmw_s[16];
    __shared__ unsigned short keptIdx[POST];
    __shared__ int sTotal;
    int img = blockIdx.x;
    int t = threadIdx.x;
    const unsigned long long* mbase = masks + (size_t)img * PRE * 16;
    {
        const ulonglong2* src = (const ulonglong2*)mbase;
        ulonglong2* dst = (ulonglong2*)lm;
#pragma unroll
        for (int k = 0; k < 8; ++k) dst[t + k * 1024] = src[t + k * 1024];
    }
    {   // vmask from varr: wave w covers ranks w*64..w*64+63
        unsigned long long bal = __ballot(varr[img * PRE + t] != 0u);
        if ((t & 63) == 0) vmw_s[t >> 6] = bal;
    }
    __syncthreads();

    if (t < 64) {
        int lane = t;
        int lw = lane & 15;
        unsigned long long vmw = vmw_s[lw];
        unsigned long long supw = 0ULL;
        int cnt = 0;
        for (int b = 0; b < 16 && cnt < POST; ++b) {
            unsigned long long avail = readlane64(vmw, b) & ~readlane64(supw, b);
            while (avail && cnt < POST) {
                unsigned long long a = avail;
                int d0 = __ffsll((long long)a) - 1; a &= a - 1;
                int d1 = a ? __ffsll((long long)a) - 1 : 64; a &= a - 1;
                int d2 = a ? __ffsll((long long)a) - 1 : 64; a &= a - 1;
                int d3 = a ? __ffsll((long long)a) - 1 : 64; a &= a - 1;
                int r0 = b * 64 + d0;
                int r1 = b * 64 + (d1 & 63);
                int r2 = b * 64 + (d2 & 63);
                int r3 = b * 64 + (d3 & 63);
                unsigned long long w0 = lm[r0 * 16 + lw];
                unsigned long long w1 = lm[r1 * 16 + lw];
                unsigned long long w2 = lm[r2 * 16 + lw];
                unsigned long long w3 = lm[r3 * 16 + lw];
                unsigned long long sb = readlane64(w0, b);
                supw |= w0;
                if (lane == 0) keptIdx[cnt] = (unsigned short)r0;
                ++cnt;
                if (d1 < 64 && cnt < POST && !((sb >> d1) & 1ULL)) {
                    sb |= readlane64(w1, b); supw |= w1;
                    if (lane == 0) keptIdx[cnt] = (unsigned short)r1;
                    ++cnt;
                }
                if (d2 < 64 && cnt < POST && !((sb >> d2) & 1ULL)) {
                    sb |= readlane64(w2, b); supw |= w2;
                    if (lane == 0) keptIdx[cnt] = (unsigned short)r2;
                    ++cnt;
                }
                if (d3 < 64 && cnt < POST && !((sb >> d3) & 1ULL)) {
                    sb |= readlane64(w3, b); supw |= w3;
                    if (lane == 0) keptIdx[cnt] = (unsigned short)r3;
                    ++cnt;
                }
                avail = a & ~sb;
            }
        }
        if (lane == 0) sTotal = cnt;
    }
    __syncthreads();

    int total = sTotal;
    if (t < POST) {
        float v0 = 0.f, v1 = 0.f, v2 = 0.f, v3 = 0.f, v4 = 0.f, v5 = 0.f;
        if (t < total) {
            int i = keptIdx[t];
            const float* b = boxes + (size_t)(img * PRE + i) * 5;
            v0 = b[0]; v1 = b[1]; v2 = b[2]; v3 = b[3]; v4 = b[4];
            v5 = tscr[img * PRE + i];
        }
        float* o2 = out + (size_t)(img * POST + t) * 6;
        o2[0] = v0; o2[1] = v1; o2[2] = v2; o2[3] = v3; o2[4] = v4; o2[5] = v5;
    }
}

// ---------- workspace layout (16-byte aligned where vector-cast) ----------
enum : size_t {
    OFF_BOX   = 0,         // 2*1024*5*4   = 40960
    OFF_CORN  = 40960,     // 2*1024*8*4   = 65536  -> 106496  (16-aligned, float4)
    OFF_CIRC  = 106496,    // 2*1024*16    = 32768  -> 139264  (float4)
    OFF_VARR  = 139264,    // 2048*4       = 8192   -> 147456
    OFF_TSCR  = 147456,    // 8192                  -> 155648
    OFF_MASK  = 155648,    // 2*1024*16*8  = 262144 -> 417792  (16-aligned, ulonglong2)
    OFF_PHIST = 417792,    // 16*4096*4    = 262144 -> 679936
    OFF_CNTS  = 679936,    // 32                    -> 679968
    OFF_SELB  = 679968,    // 16                    -> 679984
    OFF_CBUF  = 679984,    // 2*4096*8     = 65536  -> 745520
};

extern "C" void kernel_launch(void* const* d_in, const int* in_sizes, int n_in,
                              void* d_out, int out_size, void* d_ws, size_t ws_size,
                              hipStream_t stream) {
    const float* obj = (const float*)d_in[0];       // (2,1,256,256) f32
    const float* boxreg = (const float*)d_in[1];    // (2,5,256,256) f32
    float* out = (float*)d_out;                     // (2,256,6) f32

    char* w = (char*)d_ws;
    float* boxes = (float*)(w + OFF_BOX);
    float* corn = (float*)(w + OFF_CORN);
    float4* circ = (float4*)(w + OFF_CIRC);
    unsigned int* varr = (unsigned int*)(w + OFF_VARR);
    float* tscr = (float*)(w + OFF_TSCR);
    unsigned long long* masks = (unsigned long long*)(w + OFF_MASK);
    unsigned int* phist = (unsigned int*)(w + OFF_PHIST);
    unsigned int* cnts = (unsigned int*)(w + OFF_CNTS);
    unsigned int* selB = (unsigned int*)(w + OFF_SELB);
    unsigned long long* cbuf = (unsigned long long*)(w + OFF_CBUF);

    k_front<<<16, 1024, 0, stream>>>(obj, phist, masks, cnts);
    k_findbin<<<N_IMG, 256, 0, stream>>>(phist, selB);
    k_compact<<<64, 256, 0, stream>>>(obj, selB, cnts, cbuf);
    k_rankdec<<<32, 256, 0, stream>>>(cnts, cbuf, boxreg, boxes, corn, circ, varr, tscr);
    k_pairclip<<<512, 256, 0, stream>>>(circ, corn, masks);
    k_nms_out<<<N_IMG, 1024, 0, stream>>>(masks, varr, boxes, tscr, out);
}